// Round 1
// baseline (2274.205 us; speedup 1.0000x reference)
//
#include <hip/hip_runtime.h>
#include <math.h>

#define HH 64
#define WW 64
#define BATCH 16
#define CINX 16
#define CHID 128
#define LNK 5

// ws layout (floats)
#define OFF_F      0
#define N_F        (BATCH*32*HH*WW)          // 2097152
#define OFF_FLOWS  (OFF_F + N_F)
#define N_FLOWS    (BATCH*2*LNK*HH*WW)       // 655360
#define OFF_WXRT   (OFF_FLOWS + N_FLOWS)     // 2752512
#define N_WXT      (400*128)                 // 51200
#define OFF_WXHT   (OFF_WXRT + N_WXT)
#define OFF_WRT    (OFF_WXHT + N_WXT)
#define N_WT       (640*128)                 // 81920
#define OFF_WHT    (OFF_WRT + N_WT)
#define OFF_BRS    (OFF_WHT + N_WT)
#define OFF_BHS    (OFF_BRS + 128)

// ---------------- prep: transpose weights, pre-sum biases ----------------
__global__ __launch_bounds__(256) void prep_kernel(
    const float* __restrict__ wxr_w, const float* __restrict__ wxh_w,
    const float* __restrict__ whr_w, const float* __restrict__ whh_w,
    const float* __restrict__ whr_b, const float* __restrict__ whh_b,
    float* __restrict__ wxrT, float* __restrict__ wxhT,
    float* __restrict__ wrT,  float* __restrict__ whT,
    float* __restrict__ brs,  float* __restrict__ bhs)
{
  int i = blockIdx.x * 256 + threadIdx.x;
  if (i < N_WXT) {
    int k = i >> 7, o = i & 127;            // wx_w: [o][400] -> [k][o]
    wxrT[i] = wxr_w[o*400 + k];
    wxhT[i] = wxh_w[o*400 + k];
  } else if (i < N_WXT + N_WT) {
    int j = i - N_WXT;
    int lc = j >> 7, o = j & 127;           // wh_w: [l][o][c] -> [lc][o]
    int l = lc >> 7, c = lc & 127;
    wrT[j] = whr_w[(l*128 + o)*128 + c];
    whT[j] = whh_w[(l*128 + o)*128 + c];
  } else if (i < N_WXT + N_WT + 128) {
    int o = i - (N_WXT + N_WT);
    float sr = 0.f, sh = 0.f;
    for (int l = 0; l < LNK; ++l) { sr += whr_b[l*128 + o]; sh += whh_b[l*128 + o]; }
    brs[o] = sr; bhs[o] = sh;
  }
}

// ---------------- f = leaky_relu(conv(x,gx)+conv(h,gh)) ----------------
__global__ __launch_bounds__(256) void fgen_kernel(
    const float* __restrict__ x, const float* __restrict__ h,
    const float* __restrict__ gxw, const float* __restrict__ gxb,
    const float* __restrict__ ghw, const float* __restrict__ ghb,
    float* __restrict__ f)
{
  __shared__ float tile[20*20];
  const int b = blockIdx.z;
  const int ty0 = blockIdx.y * 16, tx0 = blockIdx.x * 16;
  const int t = threadIdx.x;
  const int ty = t >> 4, tx = t & 15;
  float acc[32];
  #pragma unroll
  for (int o = 0; o < 32; ++o) acc[o] = gxb[o] + ghb[o];

  #pragma unroll 1
  for (int cin = 0; cin < CINX; ++cin) {
    const float* src = x + (b*CINX + cin)*HH*WW;
    __syncthreads();
    for (int i = t; i < 400; i += 256) {
      int r = i / 20, c = i % 20;
      int gy = ty0 + r - 2, gx = tx0 + c - 2;
      tile[i] = (gy >= 0 && gy < HH && gx >= 0 && gx < WW) ? src[gy*WW + gx] : 0.f;
    }
    __syncthreads();
    float v[25];
    #pragma unroll
    for (int k = 0; k < 25; ++k) v[k] = tile[(ty + k/5)*20 + tx + (k%5)];
    const float* wp = gxw + cin*25;
    #pragma unroll
    for (int o = 0; o < 32; ++o) {
      #pragma unroll
      for (int k = 0; k < 25; ++k) acc[o] = fmaf(v[k], wp[o*(CINX*25) + k], acc[o]);
    }
  }
  #pragma unroll 1
  for (int cin = 0; cin < CHID; ++cin) {
    const float* src = h + (b*CHID + cin)*HH*WW;
    __syncthreads();
    for (int i = t; i < 400; i += 256) {
      int r = i / 20, c = i % 20;
      int gy = ty0 + r - 2, gx = tx0 + c - 2;
      tile[i] = (gy >= 0 && gy < HH && gx >= 0 && gx < WW) ? src[gy*WW + gx] : 0.f;
    }
    __syncthreads();
    float v[25];
    #pragma unroll
    for (int k = 0; k < 25; ++k) v[k] = tile[(ty + k/5)*20 + tx + (k%5)];
    const float* wp = ghw + cin*25;
    #pragma unroll
    for (int o = 0; o < 32; ++o) {
      #pragma unroll
      for (int k = 0; k < 25; ++k) acc[o] = fmaf(v[k], wp[o*(CHID*25) + k], acc[o]);
    }
  }
  const int oi = (ty0+ty)*WW + tx0 + tx;
  #pragma unroll
  for (int o = 0; o < 32; ++o) {
    float a = acc[o];
    f[(b*32 + o)*HH*WW + oi] = a >= 0.f ? a : 0.2f*a;
  }
}

// ---------------- flows = conv(f, gf) ----------------
__global__ __launch_bounds__(256) void flowc_kernel(
    const float* __restrict__ f, const float* __restrict__ gfw,
    const float* __restrict__ gfb, float* __restrict__ flows)
{
  __shared__ float tile[20*20];
  const int b = blockIdx.z;
  const int ty0 = blockIdx.y * 16, tx0 = blockIdx.x * 16;
  const int t = threadIdx.x;
  const int ty = t >> 4, tx = t & 15;
  float acc[10];
  #pragma unroll
  for (int o = 0; o < 10; ++o) acc[o] = gfb[o];

  #pragma unroll 1
  for (int cin = 0; cin < 32; ++cin) {
    const float* src = f + (b*32 + cin)*HH*WW;
    __syncthreads();
    for (int i = t; i < 400; i += 256) {
      int r = i / 20, c = i % 20;
      int gy = ty0 + r - 2, gx = tx0 + c - 2;
      tile[i] = (gy >= 0 && gy < HH && gx >= 0 && gx < WW) ? src[gy*WW + gx] : 0.f;
    }
    __syncthreads();
    float v[25];
    #pragma unroll
    for (int k = 0; k < 25; ++k) v[k] = tile[(ty + k/5)*20 + tx + (k%5)];
    const float* wp = gfw + cin*25;
    #pragma unroll
    for (int o = 0; o < 10; ++o) {
      #pragma unroll
      for (int k = 0; k < 25; ++k) acc[o] = fmaf(v[k], wp[o*(32*25) + k], acc[o]);
    }
  }
  const int oi = (ty0+ty)*WW + tx0 + tx;
  #pragma unroll
  for (int o = 0; o < 10; ++o) flows[(b*10 + o)*HH*WW + oi] = acc[o];
}

// ---------------- fused warp + gates + output ----------------
__global__ __launch_bounds__(256) void fuse_kernel(
    const float* __restrict__ x, const float* __restrict__ h,
    const float* __restrict__ flows,
    const float* __restrict__ wxrT, const float* __restrict__ wxhT,
    const float* __restrict__ wrT,  const float* __restrict__ whT,
    const float* __restrict__ wxrb, const float* __restrict__ wxhb,
    const float* __restrict__ brs,  const float* __restrict__ bhs,
    float* __restrict__ out, int out_half)
{
  __shared__ float xtile[CINX*5*36];        // 2880 floats
  __shared__ float warped[LNK*CHID*32];     // 20480 floats (81.9 KB)
  __shared__ int   cidx[LNK*4*32];          // [l][corner][pos]
  __shared__ float cwt[LNK*4*32];

  const int t = threadIdx.x;
  const int bid = blockIdx.x;
  const int b = bid >> 7;
  const int rem = bid & 127;
  const int y = rem >> 1;
  const int xb = (rem & 1) << 5;            // 0 or 32

  // stage x halo tile: rows y-2..y+2, cols xb-2..xb+33
  {
    const float* xp = x + b*CINX*HH*WW;
    for (int i = t; i < CINX*5*36; i += 256) {
      int cin = i / 180; int r2 = i % 180; int rr = r2 / 36; int cc = r2 % 36;
      int gy = y + rr - 2, gx = xb + cc - 2;
      xtile[i] = (gy >= 0 && gy < HH && gx >= 0 && gx < WW) ? xp[cin*HH*WW + gy*WW + gx] : 0.f;
    }
  }
  // bilinear corner indices/weights for 32 pos x 5 links
  if (t < 160) {
    int pos = t & 31; int l = t >> 5;
    int gx = xb + pos;
    float fx = flows[((b*2*LNK) + 2*l + 0)*HH*WW + y*WW + gx];
    float fy = flows[((b*2*LNK) + 2*l + 1)*HH*WW + y*WW + gx];
    float px = fx + (float)gx;
    float py = fy + (float)y;
    float x0f = floorf(px), y0f = floorf(py);
    float ax = px - x0f, ay = py - y0f;
    int ix0 = (int)x0f, iy0 = (int)y0f;
    #pragma unroll
    for (int k = 0; k < 4; ++k) {
      int dx = k & 1, dy = k >> 1;
      int ix = ix0 + dx, iy = iy0 + dy;
      float wgt = (dx ? ax : 1.f - ax) * (dy ? ay : 1.f - ay);
      bool inb = (ix >= 0 && ix < WW && iy >= 0 && iy < HH);
      int ixc = ix < 0 ? 0 : (ix > WW-1 ? WW-1 : ix);
      int iyc = iy < 0 ? 0 : (iy > HH-1 ? HH-1 : iy);
      cidx[(l*4 + k)*32 + pos] = iyc*WW + ixc;
      cwt [(l*4 + k)*32 + pos] = inb ? wgt : 0.f;
    }
  }
  __syncthreads();

  // gather warped[lc][pos]
  {
    const float* hp = h + b*CHID*HH*WW;
    const int pos = t & 31;
    #pragma unroll 1
    for (int j = 0; j < 80; ++j) {
      int lc = (t >> 5) + j*8;
      int l = lc >> 7, c = lc & 127;
      const float* hc = hp + c*HH*WW;
      float a = 0.f;
      #pragma unroll
      for (int k = 0; k < 4; ++k) {
        float wgt = cwt[(l*4 + k)*32 + pos];
        int idx   = cidx[(l*4 + k)*32 + pos];
        a = fmaf(wgt, hc[idx], a);
      }
      warped[lc*32 + pos] = a;
    }
  }
  __syncthreads();

  // per-thread 4o x 4pos register tile
  const int og = (t & 31) << 2;   // 0..124
  const int pg = t >> 5;          // 0..7
  const int p0 = pg << 2;
  float accr[4][4], chv[4][4], thv[4][4];
  #pragma unroll
  for (int i = 0; i < 4; ++i) {
    float br = wxrb[og+i] + brs[og+i];
    float bh = wxhb[og+i];
    float bt = bhs[og+i];
    #pragma unroll
    for (int j = 0; j < 4; ++j) { accr[i][j] = br; chv[i][j] = bh; thv[i][j] = bt; }
  }

  // x-conv part: conv(x,wxr) -> accr ; conv(x,wxh) -> chv
  #pragma unroll 1
  for (int cin = 0; cin < CINX; ++cin) {
    #pragma unroll
    for (int kh = 0; kh < 5; ++kh) {
      #pragma unroll
      for (int kw = 0; kw < 5; ++kw) {
        int k = (cin*5 + kh)*5 + kw;
        float4 wr = *(const float4*)&wxrT[k*128 + og];
        float4 wh = *(const float4*)&wxhT[k*128 + og];
        int ta = cin*180 + kh*36 + p0 + kw;
        float vv0 = xtile[ta+0], vv1 = xtile[ta+1], vv2 = xtile[ta+2], vv3 = xtile[ta+3];
        float vv[4] = {vv0, vv1, vv2, vv3};
        float wrv[4] = {wr.x, wr.y, wr.z, wr.w};
        float whv[4] = {wh.x, wh.y, wh.z, wh.w};
        #pragma unroll
        for (int i = 0; i < 4; ++i)
          #pragma unroll
          for (int j = 0; j < 4; ++j) {
            accr[i][j] = fmaf(wrv[i], vv[j], accr[i][j]);
            chv[i][j]  = fmaf(whv[i], vv[j], chv[i][j]);
          }
      }
    }
  }

  // warped einsum part: temp_r -> accr ; temp_h -> thv
  #pragma unroll 2
  for (int lc = 0; lc < 640; ++lc) {
    float4 wr = *(const float4*)&wrT[lc*128 + og];
    float4 wh = *(const float4*)&whT[lc*128 + og];
    float4 v  = *(const float4*)&warped[lc*32 + p0];
    float vv[4] = {v.x, v.y, v.z, v.w};
    float wrv[4] = {wr.x, wr.y, wr.z, wr.w};
    float whv[4] = {wh.x, wh.y, wh.z, wh.w};
    #pragma unroll
    for (int i = 0; i < 4; ++i)
      #pragma unroll
      for (int j = 0; j < 4; ++j) {
        accr[i][j] = fmaf(wrv[i], vv[j], accr[i][j]);
        thv[i][j]  = fmaf(whv[i], vv[j], thv[i][j]);
      }
  }

  // finish: r = sigmoid(convr+tempr); out = leaky(convh + r*temph); z cancels.
  const int obase = (b*CHID)*HH*WW + y*WW + xb;
  #pragma unroll
  for (int i = 0; i < 4; ++i)
    #pragma unroll
    for (int j = 0; j < 4; ++j) {
      float r = 1.f / (1.f + expf(-accr[i][j]));
      float hv = chv[i][j] + r * thv[i][j];
      hv = hv >= 0.f ? hv : 0.2f * hv;
      int idx = obase + (og + i)*HH*WW + p0 + j;
      out[idx] = hv;
      out[out_half + idx] = hv;
    }
}

extern "C" void kernel_launch(void* const* d_in, const int* in_sizes, int n_in,
                              void* d_out, int out_size, void* d_ws, size_t ws_size,
                              hipStream_t stream)
{
  const float* x     = (const float*)d_in[0];
  const float* h     = (const float*)d_in[1];
  const float* gx_w  = (const float*)d_in[2];
  const float* gx_b  = (const float*)d_in[3];
  const float* gh_w  = (const float*)d_in[4];
  const float* gh_b  = (const float*)d_in[5];
  const float* gf_w  = (const float*)d_in[6];
  const float* gf_b  = (const float*)d_in[7];
  const float* wxr_w = (const float*)d_in[10];
  const float* wxr_b = (const float*)d_in[11];
  const float* wxh_w = (const float*)d_in[12];
  const float* wxh_b = (const float*)d_in[13];
  const float* whr_w = (const float*)d_in[16];
  const float* whr_b = (const float*)d_in[17];
  const float* whh_w = (const float*)d_in[18];
  const float* whh_b = (const float*)d_in[19];
  float* out = (float*)d_out;
  float* wsf = (float*)d_ws;

  float* f_buf = wsf + OFF_F;
  float* flows = wsf + OFF_FLOWS;
  float* wxrT  = wsf + OFF_WXRT;
  float* wxhT  = wsf + OFF_WXHT;
  float* wrT   = wsf + OFF_WRT;
  float* whT   = wsf + OFF_WHT;
  float* brs   = wsf + OFF_BRS;
  float* bhs   = wsf + OFF_BHS;

  prep_kernel<<<(N_WXT + N_WT + 128 + 255)/256, 256, 0, stream>>>(
      wxr_w, wxh_w, whr_w, whh_w, whr_b, whh_b, wxrT, wxhT, wrT, whT, brs, bhs);
  fgen_kernel<<<dim3(4,4,BATCH), 256, 0, stream>>>(x, h, gx_w, gx_b, gh_w, gh_b, f_buf);
  flowc_kernel<<<dim3(4,4,BATCH), 256, 0, stream>>>(f_buf, gf_w, gf_b, flows);
  fuse_kernel<<<BATCH*128, 256, 0, stream>>>(x, h, flows, wxrT, wxhT, wrT, whT,
                                             wxr_b, wxh_b, brs, bhs, out, out_size/2);
}

// Round 2
// 1824.866 us; speedup vs baseline: 1.2462x; 1.2462x over previous
//
#include <hip/hip_runtime.h>
#include <math.h>

#define HH 64
#define WW 64
#define BATCH 16
#define CINX 16
#define CHID 128
#define LNK 5

// ws layout (floats)
#define OFF_F      0
#define N_F        (BATCH*32*HH*WW)          // 2097152
#define OFF_FLOWS  (OFF_F + N_F)
#define N_FLOWS    (BATCH*2*LNK*HH*WW)       // 655360
#define OFF_WXRT   (OFF_FLOWS + N_FLOWS)     // 2752512
#define N_WXT      (400*128)                 // 51200
#define OFF_WXHT   (OFF_WXRT + N_WXT)
#define OFF_WRT    (OFF_WXHT + N_WXT)
#define N_WT       (640*128)                 // 81920
#define OFF_WHT    (OFF_WRT + N_WT)
#define OFF_BRS    (OFF_WHT + N_WT)
#define OFF_BHS    (OFF_BRS + 128)

// ---------------- prep: transpose weights, pre-sum biases ----------------
__global__ __launch_bounds__(256) void prep_kernel(
    const float* __restrict__ wxr_w, const float* __restrict__ wxh_w,
    const float* __restrict__ whr_w, const float* __restrict__ whh_w,
    const float* __restrict__ whr_b, const float* __restrict__ whh_b,
    float* __restrict__ wxrT, float* __restrict__ wxhT,
    float* __restrict__ wrT,  float* __restrict__ whT,
    float* __restrict__ brs,  float* __restrict__ bhs)
{
  int i = blockIdx.x * 256 + threadIdx.x;
  if (i < N_WXT) {
    int k = i >> 7, o = i & 127;            // wx_w: [o][400] -> [k][o]
    wxrT[i] = wxr_w[o*400 + k];
    wxhT[i] = wxh_w[o*400 + k];
  } else if (i < N_WXT + N_WT) {
    int j = i - N_WXT;
    int lc = j >> 7, o = j & 127;           // wh_w: [l][o][c] -> [lc][o]
    int l = lc >> 7, c = lc & 127;
    wrT[j] = whr_w[(l*128 + o)*128 + c];
    whT[j] = whh_w[(l*128 + o)*128 + c];
  } else if (i < N_WXT + N_WT + 128) {
    int o = i - (N_WXT + N_WT);
    float sr = 0.f, sh = 0.f;
    for (int l = 0; l < LNK; ++l) { sr += whr_b[l*128 + o]; sh += whh_b[l*128 + o]; }
    brs[o] = sr; bhs[o] = sh;
  }
}

// ---------------- f = leaky_relu(conv(x,gx)+conv(h,gh)) ----------------
__global__ __launch_bounds__(256) void fgen_kernel(
    const float* __restrict__ x, const float* __restrict__ h,
    const float* __restrict__ gxw, const float* __restrict__ gxb,
    const float* __restrict__ ghw, const float* __restrict__ ghb,
    float* __restrict__ f)
{
  __shared__ float tile[20*20];
  const int b = blockIdx.z;
  const int ty0 = blockIdx.y * 16, tx0 = blockIdx.x * 16;
  const int t = threadIdx.x;
  const int ty = t >> 4, tx = t & 15;
  float acc[32];
  #pragma unroll
  for (int o = 0; o < 32; ++o) acc[o] = gxb[o] + ghb[o];

  #pragma unroll 1
  for (int cin = 0; cin < CINX; ++cin) {
    const float* src = x + (b*CINX + cin)*HH*WW;
    __syncthreads();
    for (int i = t; i < 400; i += 256) {
      int r = i / 20, c = i % 20;
      int gy = ty0 + r - 2, gx = tx0 + c - 2;
      tile[i] = (gy >= 0 && gy < HH && gx >= 0 && gx < WW) ? src[gy*WW + gx] : 0.f;
    }
    __syncthreads();
    float v[25];
    #pragma unroll
    for (int k = 0; k < 25; ++k) v[k] = tile[(ty + k/5)*20 + tx + (k%5)];
    const float* wp = gxw + cin*25;
    #pragma unroll
    for (int o = 0; o < 32; ++o) {
      #pragma unroll
      for (int k = 0; k < 25; ++k) acc[o] = fmaf(v[k], wp[o*(CINX*25) + k], acc[o]);
    }
  }
  #pragma unroll 1
  for (int cin = 0; cin < CHID; ++cin) {
    const float* src = h + (b*CHID + cin)*HH*WW;
    __syncthreads();
    for (int i = t; i < 400; i += 256) {
      int r = i / 20, c = i % 20;
      int gy = ty0 + r - 2, gx = tx0 + c - 2;
      tile[i] = (gy >= 0 && gy < HH && gx >= 0 && gx < WW) ? src[gy*WW + gx] : 0.f;
    }
    __syncthreads();
    float v[25];
    #pragma unroll
    for (int k = 0; k < 25; ++k) v[k] = tile[(ty + k/5)*20 + tx + (k%5)];
    const float* wp = ghw + cin*25;
    #pragma unroll
    for (int o = 0; o < 32; ++o) {
      #pragma unroll
      for (int k = 0; k < 25; ++k) acc[o] = fmaf(v[k], wp[o*(CHID*25) + k], acc[o]);
    }
  }
  const int oi = (ty0+ty)*WW + tx0 + tx;
  #pragma unroll
  for (int o = 0; o < 32; ++o) {
    float a = acc[o];
    f[(b*32 + o)*HH*WW + oi] = a >= 0.f ? a : 0.2f*a;
  }
}

// ---------------- flows = conv(f, gf) ----------------
__global__ __launch_bounds__(256) void flowc_kernel(
    const float* __restrict__ f, const float* __restrict__ gfw,
    const float* __restrict__ gfb, float* __restrict__ flows)
{
  __shared__ float tile[20*20];
  const int b = blockIdx.z;
  const int ty0 = blockIdx.y * 16, tx0 = blockIdx.x * 16;
  const int t = threadIdx.x;
  const int ty = t >> 4, tx = t & 15;
  float acc[10];
  #pragma unroll
  for (int o = 0; o < 10; ++o) acc[o] = gfb[o];

  #pragma unroll 1
  for (int cin = 0; cin < 32; ++cin) {
    const float* src = f + (b*32 + cin)*HH*WW;
    __syncthreads();
    for (int i = t; i < 400; i += 256) {
      int r = i / 20, c = i % 20;
      int gy = ty0 + r - 2, gx = tx0 + c - 2;
      tile[i] = (gy >= 0 && gy < HH && gx >= 0 && gx < WW) ? src[gy*WW + gx] : 0.f;
    }
    __syncthreads();
    float v[25];
    #pragma unroll
    for (int k = 0; k < 25; ++k) v[k] = tile[(ty + k/5)*20 + tx + (k%5)];
    const float* wp = gfw + cin*25;
    #pragma unroll
    for (int o = 0; o < 10; ++o) {
      #pragma unroll
      for (int k = 0; k < 25; ++k) acc[o] = fmaf(v[k], wp[o*(32*25) + k], acc[o]);
    }
  }
  const int oi = (ty0+ty)*WW + tx0 + tx;
  #pragma unroll
  for (int o = 0; o < 10; ++o) flows[(b*10 + o)*HH*WW + oi] = acc[o];
}

// ---------------- fused warp + gates + output (row-per-block, chunked K) ---
// block = (b, y): 64 positions, 512 threads, thread tile = 4o x 4pos.
// LDS: xtile 16x5x68 (21.8KB) + corners (10KB) + warped chunk 128x64 (32KB)
//      = 63.3KB -> 2 blocks/CU -> 4 waves/SIMD.
__global__ void fuse2_kernel(
    const float* __restrict__ x, const float* __restrict__ h,
    const float* __restrict__ flows,
    const float* __restrict__ wxrT, const float* __restrict__ wxhT,
    const float* __restrict__ wrT,  const float* __restrict__ whT,
    const float* __restrict__ wxrb, const float* __restrict__ wxhb,
    const float* __restrict__ brs,  const float* __restrict__ bhs,
    float* __restrict__ out, int out_half)
{
  __shared__ float xtile[CINX*5*68];        // 5440 floats
  __shared__ int   cidx[LNK*4*64];          // [l][corner][pos]
  __shared__ float cwt[LNK*4*64];
  __shared__ float warped[128*64];          // one K-chunk (l fixed per chunk)

  const int t = threadIdx.x;
  const int bid = blockIdx.x;
  const int b = bid >> 6;
  const int y = bid & 63;

  // stage x halo tile: rows y-2..y+2, cols -2..65
  {
    const float* xp = x + b*CINX*HH*WW;
    for (int i = t; i < CINX*5*68; i += 512) {
      int cin = i / 340; int r2 = i % 340; int rr = r2 / 68; int cc = r2 % 68;
      int gy = y + rr - 2, gx = cc - 2;
      xtile[i] = (gy >= 0 && gy < HH && gx >= 0 && gx < WW) ? xp[cin*HH*WW + gy*WW + gx] : 0.f;
    }
  }
  // bilinear corner indices/weights for 64 pos x 5 links
  if (t < 320) {
    int pos = t & 63; int l = t >> 6;
    float fx = flows[((b*2*LNK) + 2*l + 0)*HH*WW + y*WW + pos];
    float fy = flows[((b*2*LNK) + 2*l + 1)*HH*WW + y*WW + pos];
    float px = fx + (float)pos;
    float py = fy + (float)y;
    float x0f = floorf(px), y0f = floorf(py);
    float ax = px - x0f, ay = py - y0f;
    int ix0 = (int)x0f, iy0 = (int)y0f;
    #pragma unroll
    for (int k = 0; k < 4; ++k) {
      int dx = k & 1, dy = k >> 1;
      int ix = ix0 + dx, iy = iy0 + dy;
      float wgt = (dx ? ax : 1.f - ax) * (dy ? ay : 1.f - ay);
      bool inb = (ix >= 0 && ix < WW && iy >= 0 && iy < HH);
      int ixc = ix < 0 ? 0 : (ix > WW-1 ? WW-1 : ix);
      int iyc = iy < 0 ? 0 : (iy > HH-1 ? HH-1 : iy);
      cidx[(l*4 + k)*64 + pos] = iyc*WW + ixc;
      cwt [(l*4 + k)*64 + pos] = inb ? wgt : 0.f;
    }
  }
  __syncthreads();

  // per-thread 4o x 4pos register tiles
  const int og = (t & 31) << 2;   // 0..124
  const int p0 = (t >> 5) << 2;   // 0..60
  float accr[4][4], chv[4][4], thv[4][4];
  #pragma unroll
  for (int i = 0; i < 4; ++i) {
    float br = wxrb[og+i] + brs[og+i];
    float bh = wxhb[og+i];
    float bt = bhs[og+i];
    #pragma unroll
    for (int j = 0; j < 4; ++j) { accr[i][j] = br; chv[i][j] = bh; thv[i][j] = bt; }
  }

  // x-conv: conv(x,wxr) -> accr ; conv(x,wxh) -> chv
  #pragma unroll 1
  for (int cin = 0; cin < CINX; ++cin) {
    #pragma unroll
    for (int kh = 0; kh < 5; ++kh) {
      #pragma unroll
      for (int kw = 0; kw < 5; ++kw) {
        int k = (cin*5 + kh)*5 + kw;
        float4 wr = *(const float4*)&wxrT[k*128 + og];
        float4 wh = *(const float4*)&wxhT[k*128 + og];
        int ta = cin*340 + kh*68 + p0 + kw;
        float vv[4] = {xtile[ta+0], xtile[ta+1], xtile[ta+2], xtile[ta+3]};
        float wrv[4] = {wr.x, wr.y, wr.z, wr.w};
        float whv[4] = {wh.x, wh.y, wh.z, wh.w};
        #pragma unroll
        for (int i = 0; i < 4; ++i)
          #pragma unroll
          for (int j = 0; j < 4; ++j) {
            accr[i][j] = fmaf(wrv[i], vv[j], accr[i][j]);
            chv[i][j]  = fmaf(whv[i], vv[j], chv[i][j]);
          }
      }
    }
  }

  // einsum over K=640 in 5 chunks of 128 (chunk == link l, c == lc&127)
  const float* hp = h + b*CHID*HH*WW;
  const int gpos = t & 63;
  const int lr0  = t >> 6;    // 0..7
  #pragma unroll 1
  for (int ch = 0; ch < 5; ++ch) {
    __syncthreads();
    // hoist the 4 corner (idx,wgt) for this link into registers
    float w0 = cwt[(ch*4+0)*64 + gpos], w1 = cwt[(ch*4+1)*64 + gpos];
    float w2 = cwt[(ch*4+2)*64 + gpos], w3 = cwt[(ch*4+3)*64 + gpos];
    int   i0 = cidx[(ch*4+0)*64 + gpos], i1 = cidx[(ch*4+1)*64 + gpos];
    int   i2 = cidx[(ch*4+2)*64 + gpos], i3 = cidx[(ch*4+3)*64 + gpos];
    #pragma unroll
    for (int j = 0; j < 16; ++j) {
      int c = lr0 + (j << 3);
      const float* hc = hp + c*HH*WW;
      float a = w0*hc[i0];
      a = fmaf(w1, hc[i1], a);
      a = fmaf(w2, hc[i2], a);
      a = fmaf(w3, hc[i3], a);
      warped[c*64 + gpos] = a;
    }
    __syncthreads();

    const float* wrp = wrT + (ch << 7)*128;
    const float* whp = whT + (ch << 7)*128;
    #pragma unroll 2
    for (int lcl = 0; lcl < 128; ++lcl) {
      float4 wr = *(const float4*)&wrp[lcl*128 + og];
      float4 wh = *(const float4*)&whp[lcl*128 + og];
      float4 v  = *(const float4*)&warped[lcl*64 + p0];
      float vv[4] = {v.x, v.y, v.z, v.w};
      float wrv[4] = {wr.x, wr.y, wr.z, wr.w};
      float whv[4] = {wh.x, wh.y, wh.z, wh.w};
      #pragma unroll
      for (int i = 0; i < 4; ++i)
        #pragma unroll
        for (int j = 0; j < 4; ++j) {
          accr[i][j] = fmaf(wrv[i], vv[j], accr[i][j]);
          thv[i][j]  = fmaf(whv[i], vv[j], thv[i][j]);
        }
    }
  }

  // finish: r = sigmoid(convr+tempr); out = leaky(convh + r*temph); z cancels.
  const int obase = (b*CHID)*HH*WW + y*WW;
  #pragma unroll
  for (int i = 0; i < 4; ++i) {
    float4 o4;
    float* o4p = (float*)&o4;
    #pragma unroll
    for (int j = 0; j < 4; ++j) {
      float r = 1.f / (1.f + expf(-accr[i][j]));
      float hv = chv[i][j] + r * thv[i][j];
      o4p[j] = hv >= 0.f ? hv : 0.2f * hv;
    }
    int idx = obase + (og + i)*HH*WW + p0;
    *(float4*)&out[idx] = o4;
    *(float4*)&out[out_half + idx] = o4;
  }
}

extern "C" void kernel_launch(void* const* d_in, const int* in_sizes, int n_in,
                              void* d_out, int out_size, void* d_ws, size_t ws_size,
                              hipStream_t stream)
{
  const float* x     = (const float*)d_in[0];
  const float* h     = (const float*)d_in[1];
  const float* gx_w  = (const float*)d_in[2];
  const float* gx_b  = (const float*)d_in[3];
  const float* gh_w  = (const float*)d_in[4];
  const float* gh_b  = (const float*)d_in[5];
  const float* gf_w  = (const float*)d_in[6];
  const float* gf_b  = (const float*)d_in[7];
  const float* wxr_w = (const float*)d_in[10];
  const float* wxr_b = (const float*)d_in[11];
  const float* wxh_w = (const float*)d_in[12];
  const float* wxh_b = (const float*)d_in[13];
  const float* whr_w = (const float*)d_in[16];
  const float* whr_b = (const float*)d_in[17];
  const float* whh_w = (const float*)d_in[18];
  const float* whh_b = (const float*)d_in[19];
  float* out = (float*)d_out;
  float* wsf = (float*)d_ws;

  float* f_buf = wsf + OFF_F;
  float* flows = wsf + OFF_FLOWS;
  float* wxrT  = wsf + OFF_WXRT;
  float* wxhT  = wsf + OFF_WXHT;
  float* wrT   = wsf + OFF_WRT;
  float* whT   = wsf + OFF_WHT;
  float* brs   = wsf + OFF_BRS;
  float* bhs   = wsf + OFF_BHS;

  prep_kernel<<<(N_WXT + N_WT + 128 + 255)/256, 256, 0, stream>>>(
      wxr_w, wxh_w, whr_w, whh_w, whr_b, whh_b, wxrT, wxhT, wrT, whT, brs, bhs);
  fgen_kernel<<<dim3(4,4,BATCH), 256, 0, stream>>>(x, h, gx_w, gx_b, gh_w, gh_b, f_buf);
  flowc_kernel<<<dim3(4,4,BATCH), 256, 0, stream>>>(f_buf, gf_w, gf_b, flows);
  fuse2_kernel<<<BATCH*HH, 512, 0, stream>>>(x, h, flows, wxrT, wxhT, wrT, whT,
                                             wxr_b, wxh_b, brs, bhs, out, out_size/2);
}

// Round 3
// 1223.035 us; speedup vs baseline: 1.8595x; 1.4921x over previous
//
#include <hip/hip_runtime.h>
#include <math.h>

#define HH 64
#define WW 64
#define BATCH 16
#define CINX 16
#define CHID 128
#define LNK 5

// ws layout (floats)
#define OFF_F      0
#define N_F        (BATCH*32*HH*WW)          // 2097152
#define OFF_FLOWS  (OFF_F + N_F)
#define N_FLOWS    (BATCH*2*LNK*HH*WW)       // 655360
#define OFF_WXRT   (OFF_FLOWS + N_FLOWS)     // 2752512
#define N_WXT      (400*128)                 // 51200
#define OFF_WXHT   (OFF_WXRT + N_WXT)
#define OFF_WRT    (OFF_WXHT + N_WXT)
#define N_WT       (640*128)                 // 81920
#define OFF_WHT    (OFF_WRT + N_WT)
#define OFF_BRS    (OFF_WHT + N_WT)
#define OFF_BHS    (OFF_BRS + 128)
#define OFF_WG     (OFF_BHS + 128)
#define N_WG       (144*25*32)               // 115200
#define OFF_WF     (OFF_WG + N_WG)
#define N_WF       (32*25*10)                // 8000

#define PREP_TOT   (N_WXT + N_WT + 128 + N_WG + N_WF)

// ---------------- prep: transpose weights, pre-sum biases ----------------
__global__ __launch_bounds__(256) void prep_kernel(
    const float* __restrict__ wxr_w, const float* __restrict__ wxh_w,
    const float* __restrict__ whr_w, const float* __restrict__ whh_w,
    const float* __restrict__ whr_b, const float* __restrict__ whh_b,
    const float* __restrict__ gx_w,  const float* __restrict__ gh_w,
    const float* __restrict__ gf_w,
    float* __restrict__ wxrT, float* __restrict__ wxhT,
    float* __restrict__ wrT,  float* __restrict__ whT,
    float* __restrict__ brs,  float* __restrict__ bhs,
    float* __restrict__ wgT,  float* __restrict__ wfT)
{
  int i = blockIdx.x * 256 + threadIdx.x;
  if (i < N_WXT) {
    int k = i >> 7, o = i & 127;            // wx_w: [o][400] -> [k][o]
    wxrT[i] = wxr_w[o*400 + k];
    wxhT[i] = wxh_w[o*400 + k];
  } else if (i < N_WXT + N_WT) {
    int j = i - N_WXT;
    int lc = j >> 7, o = j & 127;           // wh_w: [l][o][c] -> [lc][o]
    int l = lc >> 7, c = lc & 127;
    wrT[j] = whr_w[(l*128 + o)*128 + c];
    whT[j] = whh_w[(l*128 + o)*128 + c];
  } else if (i < N_WXT + N_WT + 128) {
    int o = i - (N_WXT + N_WT);
    float sr = 0.f, sh = 0.f;
    for (int l = 0; l < LNK; ++l) { sr += whr_b[l*128 + o]; sh += whh_b[l*128 + o]; }
    brs[o] = sr; bhs[o] = sh;
  } else if (i < N_WXT + N_WT + 128 + N_WG) {
    int j = i - (N_WXT + N_WT + 128);       // wgT[k][o], k = cin*25+tap, o<32
    int k = j >> 5, o = j & 31;
    int cin = k / 25, tap = k % 25;
    wgT[j] = (cin < CINX) ? gx_w[(o*CINX + cin)*25 + tap]
                          : gh_w[(o*CHID + (cin - CINX))*25 + tap];
  } else if (i < PREP_TOT) {
    int j = i - (N_WXT + N_WT + 128 + N_WG); // wfT[k][o], k = cin*25+tap, o<10
    int k = j / 10, o = j % 10;
    int cin = k / 25, tap = k % 25;
    wfT[j] = gf_w[(o*32 + cin)*25 + tap];
  }
}

// ------- f = leaky_relu(conv(x,gx)+conv(h,gh)), row-per-block -------
// block=(b,y), 512 threads: o=t&31, 4 positions p0=(t>>5)*4.
// 9 chunks of 16 input channels (chunk0=x, 1..8=h) staged as 16x5x68 tiles.
__global__ __launch_bounds__(512) void fgen2_kernel(
    const float* __restrict__ x, const float* __restrict__ h,
    const float* __restrict__ wgT,
    const float* __restrict__ gxb, const float* __restrict__ ghb,
    float* __restrict__ f)
{
  __shared__ float tile[16*5*68];           // 5440 floats = 21.8 KB
  const int t = threadIdx.x;
  const int b = blockIdx.x >> 6;
  const int y = blockIdx.x & 63;
  const int o = t & 31;
  const int p0 = (t >> 5) << 2;

  float acc[4];
  {
    float bias = gxb[o] + ghb[o];
    acc[0] = acc[1] = acc[2] = acc[3] = bias;
  }

  #pragma unroll 1
  for (int ch = 0; ch < 9; ++ch) {
    const float* src = (ch == 0) ? (x + b*CINX*HH*WW)
                                 : (h + (b*CHID + (ch - 1)*16)*HH*WW);
    __syncthreads();
    for (int i = t; i < 16*5*68; i += 512) {
      int cin = i / 340, r2 = i % 340;
      int rr = r2 / 68, cc = r2 % 68;
      int gy = y + rr - 2, gx = cc - 2;
      tile[i] = (gy >= 0 && gy < HH && gx >= 0 && gx < WW)
                  ? src[cin*HH*WW + gy*WW + gx] : 0.f;
    }
    __syncthreads();
    const float* wbase = wgT + (ch*16*25)*32;
    #pragma unroll 1
    for (int ci = 0; ci < 16; ++ci) {
      #pragma unroll
      for (int kh = 0; kh < 5; ++kh) {
        float v[8];
        #pragma unroll
        for (int j = 0; j < 8; ++j) v[j] = tile[ci*340 + kh*68 + p0 + j];
        #pragma unroll
        for (int kw = 0; kw < 5; ++kw) {
          float w = wbase[((ci*5 + kh)*5 + kw)*32 + o];
          #pragma unroll
          for (int j = 0; j < 4; ++j) acc[j] = fmaf(w, v[kw + j], acc[j]);
        }
      }
    }
  }

  float4 o4; float* o4p = (float*)&o4;
  #pragma unroll
  for (int j = 0; j < 4; ++j) {
    float a = acc[j];
    o4p[j] = a >= 0.f ? a : 0.2f*a;
  }
  *(float4*)&f[(b*32 + o)*HH*WW + y*WW + p0] = o4;
}

// ------- flows = conv(f, gf), row-per-block -------
// block=(b,y), 640 threads: wave w = output channel o (0..9), lane = pos.
__global__ __launch_bounds__(640) void flowc2_kernel(
    const float* __restrict__ f, const float* __restrict__ wfT,
    const float* __restrict__ gfb, float* __restrict__ flows)
{
  __shared__ float tile[16*5*68];           // 21.8 KB, 2 chunks of 16 cin
  const int t = threadIdx.x;
  const int b = blockIdx.x >> 6;
  const int y = blockIdx.x & 63;
  const int o = t >> 6;                     // 0..9, wave-uniform
  const int pos = t & 63;

  float acc = gfb[o];

  #pragma unroll 1
  for (int ch = 0; ch < 2; ++ch) {
    const float* src = f + (b*32 + ch*16)*HH*WW;
    __syncthreads();
    for (int i = t; i < 16*5*68; i += 640) {
      int cin = i / 340, r2 = i % 340;
      int rr = r2 / 68, cc = r2 % 68;
      int gy = y + rr - 2, gx = cc - 2;
      tile[i] = (gy >= 0 && gy < HH && gx >= 0 && gx < WW)
                  ? src[cin*HH*WW + gy*WW + gx] : 0.f;
    }
    __syncthreads();
    const float* wbase = wfT + (ch*16*25)*10;
    #pragma unroll 1
    for (int ci = 0; ci < 16; ++ci) {
      #pragma unroll
      for (int kh = 0; kh < 5; ++kh) {
        #pragma unroll
        for (int kw = 0; kw < 5; ++kw) {
          float w = wbase[((ci*5 + kh)*5 + kw)*10 + o];
          acc = fmaf(w, tile[ci*340 + kh*68 + pos + kw], acc);
        }
      }
    }
  }
  flows[(b*10 + o)*HH*WW + y*WW + pos] = acc;
}

// ---------------- fused warp + gates + output (row-per-block, chunked K) ---
__global__ void fuse2_kernel(
    const float* __restrict__ x, const float* __restrict__ h,
    const float* __restrict__ flows,
    const float* __restrict__ wxrT, const float* __restrict__ wxhT,
    const float* __restrict__ wrT,  const float* __restrict__ whT,
    const float* __restrict__ wxrb, const float* __restrict__ wxhb,
    const float* __restrict__ brs,  const float* __restrict__ bhs,
    float* __restrict__ out, int out_half)
{
  __shared__ float xtile[CINX*5*68];        // 5440 floats
  __shared__ int   cidx[LNK*4*64];          // [l][corner][pos]
  __shared__ float cwt[LNK*4*64];
  __shared__ float warped[128*64];          // one K-chunk (l fixed per chunk)

  const int t = threadIdx.x;
  const int bid = blockIdx.x;
  const int b = bid >> 6;
  const int y = bid & 63;

  // stage x halo tile: rows y-2..y+2, cols -2..65
  {
    const float* xp = x + b*CINX*HH*WW;
    for (int i = t; i < CINX*5*68; i += 512) {
      int cin = i / 340; int r2 = i % 340; int rr = r2 / 68; int cc = r2 % 68;
      int gy = y + rr - 2, gx = cc - 2;
      xtile[i] = (gy >= 0 && gy < HH && gx >= 0 && gx < WW) ? xp[cin*HH*WW + gy*WW + gx] : 0.f;
    }
  }
  // bilinear corner indices/weights for 64 pos x 5 links
  if (t < 320) {
    int pos = t & 63; int l = t >> 6;
    float fx = flows[((b*2*LNK) + 2*l + 0)*HH*WW + y*WW + pos];
    float fy = flows[((b*2*LNK) + 2*l + 1)*HH*WW + y*WW + pos];
    float px = fx + (float)pos;
    float py = fy + (float)y;
    float x0f = floorf(px), y0f = floorf(py);
    float ax = px - x0f, ay = py - y0f;
    int ix0 = (int)x0f, iy0 = (int)y0f;
    #pragma unroll
    for (int k = 0; k < 4; ++k) {
      int dx = k & 1, dy = k >> 1;
      int ix = ix0 + dx, iy = iy0 + dy;
      float wgt = (dx ? ax : 1.f - ax) * (dy ? ay : 1.f - ay);
      bool inb = (ix >= 0 && ix < WW && iy >= 0 && iy < HH);
      int ixc = ix < 0 ? 0 : (ix > WW-1 ? WW-1 : ix);
      int iyc = iy < 0 ? 0 : (iy > HH-1 ? HH-1 : iy);
      cidx[(l*4 + k)*64 + pos] = iyc*WW + ixc;
      cwt [(l*4 + k)*64 + pos] = inb ? wgt : 0.f;
    }
  }
  __syncthreads();

  // per-thread 4o x 4pos register tiles
  const int og = (t & 31) << 2;   // 0..124
  const int p0 = (t >> 5) << 2;   // 0..60
  float accr[4][4], chv[4][4], thv[4][4];
  #pragma unroll
  for (int i = 0; i < 4; ++i) {
    float br = wxrb[og+i] + brs[og+i];
    float bh = wxhb[og+i];
    float bt = bhs[og+i];
    #pragma unroll
    for (int j = 0; j < 4; ++j) { accr[i][j] = br; chv[i][j] = bh; thv[i][j] = bt; }
  }

  // x-conv: conv(x,wxr) -> accr ; conv(x,wxh) -> chv
  #pragma unroll 1
  for (int cin = 0; cin < CINX; ++cin) {
    #pragma unroll
    for (int kh = 0; kh < 5; ++kh) {
      #pragma unroll
      for (int kw = 0; kw < 5; ++kw) {
        int k = (cin*5 + kh)*5 + kw;
        float4 wr = *(const float4*)&wxrT[k*128 + og];
        float4 wh = *(const float4*)&wxhT[k*128 + og];
        int ta = cin*340 + kh*68 + p0 + kw;
        float vv[4] = {xtile[ta+0], xtile[ta+1], xtile[ta+2], xtile[ta+3]};
        float wrv[4] = {wr.x, wr.y, wr.z, wr.w};
        float whv[4] = {wh.x, wh.y, wh.z, wh.w};
        #pragma unroll
        for (int i = 0; i < 4; ++i)
          #pragma unroll
          for (int j = 0; j < 4; ++j) {
            accr[i][j] = fmaf(wrv[i], vv[j], accr[i][j]);
            chv[i][j]  = fmaf(whv[i], vv[j], chv[i][j]);
          }
      }
    }
  }

  // einsum over K=640 in 5 chunks of 128 (chunk == link l)
  const float* hp = h + b*CHID*HH*WW;
  const int gpos = t & 63;
  const int lr0  = t >> 6;    // 0..7
  #pragma unroll 1
  for (int ch = 0; ch < 5; ++ch) {
    __syncthreads();
    float w0 = cwt[(ch*4+0)*64 + gpos], w1 = cwt[(ch*4+1)*64 + gpos];
    float w2 = cwt[(ch*4+2)*64 + gpos], w3 = cwt[(ch*4+3)*64 + gpos];
    int   i0 = cidx[(ch*4+0)*64 + gpos], i1 = cidx[(ch*4+1)*64 + gpos];
    int   i2 = cidx[(ch*4+2)*64 + gpos], i3 = cidx[(ch*4+3)*64 + gpos];
    #pragma unroll
    for (int j = 0; j < 16; ++j) {
      int c = lr0 + (j << 3);
      const float* hc = hp + c*HH*WW;
      float a = w0*hc[i0];
      a = fmaf(w1, hc[i1], a);
      a = fmaf(w2, hc[i2], a);
      a = fmaf(w3, hc[i3], a);
      warped[c*64 + gpos] = a;
    }
    __syncthreads();

    const float* wrp = wrT + (ch << 7)*128;
    const float* whp = whT + (ch << 7)*128;
    #pragma unroll 2
    for (int lcl = 0; lcl < 128; ++lcl) {
      float4 wr = *(const float4*)&wrp[lcl*128 + og];
      float4 wh = *(const float4*)&whp[lcl*128 + og];
      float4 v  = *(const float4*)&warped[lcl*64 + p0];
      float vv[4] = {v.x, v.y, v.z, v.w};
      float wrv[4] = {wr.x, wr.y, wr.z, wr.w};
      float whv[4] = {wh.x, wh.y, wh.z, wh.w};
      #pragma unroll
      for (int i = 0; i < 4; ++i)
        #pragma unroll
        for (int j = 0; j < 4; ++j) {
          accr[i][j] = fmaf(wrv[i], vv[j], accr[i][j]);
          thv[i][j]  = fmaf(whv[i], vv[j], thv[i][j]);
        }
    }
  }

  // finish: r = sigmoid(convr+tempr); out = leaky(convh + r*temph); z cancels.
  const int obase = (b*CHID)*HH*WW + y*WW;
  #pragma unroll
  for (int i = 0; i < 4; ++i) {
    float4 o4;
    float* o4p = (float*)&o4;
    #pragma unroll
    for (int j = 0; j < 4; ++j) {
      float r = 1.f / (1.f + expf(-accr[i][j]));
      float hv = chv[i][j] + r * thv[i][j];
      o4p[j] = hv >= 0.f ? hv : 0.2f * hv;
    }
    int idx = obase + (og + i)*HH*WW + p0;
    *(float4*)&out[idx] = o4;
    *(float4*)&out[out_half + idx] = o4;
  }
}

extern "C" void kernel_launch(void* const* d_in, const int* in_sizes, int n_in,
                              void* d_out, int out_size, void* d_ws, size_t ws_size,
                              hipStream_t stream)
{
  const float* x     = (const float*)d_in[0];
  const float* h     = (const float*)d_in[1];
  const float* gx_w  = (const float*)d_in[2];
  const float* gx_b  = (const float*)d_in[3];
  const float* gh_w  = (const float*)d_in[4];
  const float* gh_b  = (const float*)d_in[5];
  const float* gf_w  = (const float*)d_in[6];
  const float* gf_b  = (const float*)d_in[7];
  const float* wxr_w = (const float*)d_in[10];
  const float* wxr_b = (const float*)d_in[11];
  const float* wxh_w = (const float*)d_in[12];
  const float* wxh_b = (const float*)d_in[13];
  const float* whr_w = (const float*)d_in[16];
  const float* whr_b = (const float*)d_in[17];
  const float* whh_w = (const float*)d_in[18];
  const float* whh_b = (const float*)d_in[19];
  float* out = (float*)d_out;
  float* wsf = (float*)d_ws;

  float* f_buf = wsf + OFF_F;
  float* flows = wsf + OFF_FLOWS;
  float* wxrT  = wsf + OFF_WXRT;
  float* wxhT  = wsf + OFF_WXHT;
  float* wrT   = wsf + OFF_WRT;
  float* whT   = wsf + OFF_WHT;
  float* brs   = wsf + OFF_BRS;
  float* bhs   = wsf + OFF_BHS;
  float* wgT   = wsf + OFF_WG;
  float* wfT   = wsf + OFF_WF;

  prep_kernel<<<(PREP_TOT + 255)/256, 256, 0, stream>>>(
      wxr_w, wxh_w, whr_w, whh_w, whr_b, whh_b, gx_w, gh_w, gf_w,
      wxrT, wxhT, wrT, whT, brs, bhs, wgT, wfT);
  fgen2_kernel<<<BATCH*HH, 512, 0, stream>>>(x, h, wgT, gx_b, gh_b, f_buf);
  flowc2_kernel<<<BATCH*HH, 640, 0, stream>>>(f_buf, wfT, gf_b, flows);
  fuse2_kernel<<<BATCH*HH, 512, 0, stream>>>(x, h, flows, wxrT, wxhT, wrT, whT,
                                             wxr_b, wxh_b, brs, bhs, out, out_size/2);
}

// Round 4
// 716.838 us; speedup vs baseline: 3.1726x; 1.7062x over previous
//
#include <hip/hip_runtime.h>
#include <math.h>

#define HH 64
#define WW 64
#define BATCH 16
#define CINX 16
#define CHID 128
#define LNK 5

// ws layout (floats)
#define OFF_F      0
#define N_F        (BATCH*32*HH*WW)          // 2097152
#define OFF_FLOWS  (OFF_F + N_F)
#define N_FLOWS    (BATCH*2*LNK*HH*WW)       // 655360
#define OFF_WG     (OFF_FLOWS + N_FLOWS)     // 2752512
#define N_WG       (144*25*32)               // 115200
#define OFF_WF     (OFF_WG + N_WG)
#define N_WF       (32*25*10)                // 8000
#define OFF_BRS    (OFF_WF + N_WF)
#define OFF_BHS    (OFF_BRS + 128)
#define OFF_ERF    (OFF_BHS + 128)           // bf16 frags: einsum r (81920 bf16)
#define OFF_EHF    (OFF_ERF + 40960)
#define OFF_XRF    (OFF_EHF + 40960)         // bf16 frags: xconv r (53248 bf16)
#define OFF_XHF    (OFF_XRF + 26624)
// total = OFF_XHF + 26624 = 3011136 floats ~ 12 MB

// prep region boundaries (element indices)
#define P_WG   115200
#define P_WF   (P_WG + 8000)                 // 123200
#define P_B    (P_WF + 128)                  // 123328
#define P_EF   (P_B + 81920)                 // 205248
#define P_XF   (P_EF + 53248)                // 258496

typedef short bf16x8 __attribute__((ext_vector_type(8)));
typedef float f32x4  __attribute__((ext_vector_type(4)));
#define MFMA(a,b,c) __builtin_amdgcn_mfma_f32_16x16x32_bf16((a),(b),(c),0,0,0)

__device__ __forceinline__ unsigned short f2b(float f) {
  unsigned u = __builtin_bit_cast(unsigned, f);
  u += 0x7fffu + ((u >> 16) & 1u);           // RNE
  return (unsigned short)(u >> 16);
}

#define SWZ(byte, row) ((byte) ^ (((row) & 7) << 4))

// ---------------- prep: transpose/fragment weights, pre-sum biases --------
__global__ __launch_bounds__(256) void prep_kernel(
    const float* __restrict__ wxr_w, const float* __restrict__ wxh_w,
    const float* __restrict__ whr_w, const float* __restrict__ whh_w,
    const float* __restrict__ whr_b, const float* __restrict__ whh_b,
    const float* __restrict__ gx_w,  const float* __restrict__ gh_w,
    const float* __restrict__ gf_w,
    float* __restrict__ wgT,  float* __restrict__ wfT,
    float* __restrict__ brs,  float* __restrict__ bhs,
    unsigned short* __restrict__ erF, unsigned short* __restrict__ ehF,
    unsigned short* __restrict__ xrF, unsigned short* __restrict__ xhF)
{
  int i = blockIdx.x * 256 + threadIdx.x;
  if (i < P_WG) {
    int k = i >> 5, o = i & 31;              // wgT[k][o], k = cin*25+tap
    int cin = k / 25, tap = k % 25;
    wgT[i] = (cin < CINX) ? gx_w[(o*CINX + cin)*25 + tap]
                          : gh_w[(o*CHID + (cin - CINX))*25 + tap];
  } else if (i < P_WF) {
    int j = i - P_WG;                        // wfT[k][o], o<10
    int k = j / 10, o = j % 10;
    int cin = k / 25, tap = k % 25;
    wfT[j] = gf_w[(o*32 + cin)*25 + tap];
  } else if (i < P_B) {
    int o = i - P_WF;
    float sr = 0.f, sh = 0.f;
    for (int l = 0; l < LNK; ++l) { sr += whr_b[l*128 + o]; sh += whh_b[l*128 + o]; }
    brs[o] = sr; bhs[o] = sh;
  } else if (i < P_EF) {
    // einsum A-frags: j = (((l*4+ks)*8+m)*64 + lane)*8 + jj
    int j = i - P_B;
    int jj = j & 7, lane = (j >> 3) & 63, m = (j >> 9) & 7, ks = (j >> 12) & 3, l = j >> 14;
    int o = m*16 + (lane & 15);
    int c = ks*32 + ((lane >> 4) << 3) + jj;
    erF[j] = f2b(whr_w[(l*128 + o)*128 + c]);
    ehF[j] = f2b(whh_w[(l*128 + o)*128 + c]);
  } else if (i < P_XF) {
    // xconv A-frags: j = ((ks*8+m)*64 + lane)*8 + jj, k padded 400->416
    int j = i - P_EF;
    int jj = j & 7, lane = (j >> 3) & 63, m = (j >> 9) & 7, ks = j >> 12;
    int o = m*16 + (lane & 15);
    int k = ks*32 + ((lane >> 4) << 3) + jj;
    xrF[j] = (k < 400) ? f2b(wxr_w[o*400 + k]) : (unsigned short)0;
    xhF[j] = (k < 400) ? f2b(wxh_w[o*400 + k]) : (unsigned short)0;
  }
}

// ------- f = leaky_relu(conv(x,gx)+conv(h,gh)), row-per-block -------
__global__ __launch_bounds__(512) void fgen2_kernel(
    const float* __restrict__ x, const float* __restrict__ h,
    const float* __restrict__ wgT,
    const float* __restrict__ gxb, const float* __restrict__ ghb,
    float* __restrict__ f)
{
  __shared__ float tile[16*5*68];
  const int t = threadIdx.x;
  const int b = blockIdx.x >> 6;
  const int y = blockIdx.x & 63;
  const int o = t & 31;
  const int p0 = (t >> 5) << 2;

  float acc[4];
  {
    float bias = gxb[o] + ghb[o];
    acc[0] = acc[1] = acc[2] = acc[3] = bias;
  }

  #pragma unroll 1
  for (int ch = 0; ch < 9; ++ch) {
    const float* src = (ch == 0) ? (x + b*CINX*HH*WW)
                                 : (h + (b*CHID + (ch - 1)*16)*HH*WW);
    __syncthreads();
    for (int i = t; i < 16*5*68; i += 512) {
      int cin = i / 340, r2 = i % 340;
      int rr = r2 / 68, cc = r2 % 68;
      int gy = y + rr - 2, gx = cc - 2;
      tile[i] = (gy >= 0 && gy < HH && gx >= 0 && gx < WW)
                  ? src[cin*HH*WW + gy*WW + gx] : 0.f;
    }
    __syncthreads();
    const float* wbase = wgT + (ch*16*25)*32;
    #pragma unroll 1
    for (int ci = 0; ci < 16; ++ci) {
      #pragma unroll
      for (int kh = 0; kh < 5; ++kh) {
        float v[8];
        #pragma unroll
        for (int j = 0; j < 8; ++j) v[j] = tile[ci*340 + kh*68 + p0 + j];
        #pragma unroll
        for (int kw = 0; kw < 5; ++kw) {
          float w = wbase[((ci*5 + kh)*5 + kw)*32 + o];
          #pragma unroll
          for (int j = 0; j < 4; ++j) acc[j] = fmaf(w, v[kw + j], acc[j]);
        }
      }
    }
  }

  float4 o4; float* o4p = (float*)&o4;
  #pragma unroll
  for (int j = 0; j < 4; ++j) {
    float a = acc[j];
    o4p[j] = a >= 0.f ? a : 0.2f*a;
  }
  *(float4*)&f[(b*32 + o)*HH*WW + y*WW + p0] = o4;
}

// ------- flows = conv(f, gf), row-per-block -------
__global__ __launch_bounds__(640) void flowc2_kernel(
    const float* __restrict__ f, const float* __restrict__ wfT,
    const float* __restrict__ gfb, float* __restrict__ flows)
{
  __shared__ float tile[16*5*68];
  const int t = threadIdx.x;
  const int b = blockIdx.x >> 6;
  const int y = blockIdx.x & 63;
  const int o = t >> 6;
  const int pos = t & 63;

  float acc = gfb[o];

  #pragma unroll 1
  for (int ch = 0; ch < 2; ++ch) {
    const float* src = f + (b*32 + ch*16)*HH*WW;
    __syncthreads();
    for (int i = t; i < 16*5*68; i += 640) {
      int cin = i / 340, r2 = i % 340;
      int rr = r2 / 68, cc = r2 % 68;
      int gy = y + rr - 2, gx = cc - 2;
      tile[i] = (gy >= 0 && gy < HH && gx >= 0 && gx < WW)
                  ? src[cin*HH*WW + gy*WW + gx] : 0.f;
    }
    __syncthreads();
    const float* wbase = wfT + (ch*16*25)*10;
    #pragma unroll 1
    for (int ci = 0; ci < 16; ++ci) {
      #pragma unroll
      for (int kh = 0; kh < 5; ++kh) {
        #pragma unroll
        for (int kw = 0; kw < 5; ++kw) {
          float w = wbase[((ci*5 + kh)*5 + kw)*10 + o];
          acc = fmaf(w, tile[ci*340 + kh*68 + pos + kw], acc);
        }
      }
    }
  }
  flows[(b*10 + o)*HH*WW + y*WW + pos] = acc;
}

// ---------------- fuse3: MFMA warp+gates+output ----------------
// block=(b,y), 512 thr = 8 waves; wave w owns o-stripe [16w,16w+16), N=64.
// GEMM2: K=416 im2col(x) bf16 in LDS [pos][k], XOR-swizzled.
// GEMM1: 5 chunks K=128, warped bf16 [pos][c] aliased into same LDS.
__global__ __launch_bounds__(512, 4) void fuse3_kernel(
    const float* __restrict__ x, const float* __restrict__ h,
    const float* __restrict__ flows,
    const unsigned short* __restrict__ erF, const unsigned short* __restrict__ ehF,
    const unsigned short* __restrict__ xrF, const unsigned short* __restrict__ xhF,
    const float* __restrict__ wxrb, const float* __restrict__ wxhb,
    const float* __restrict__ brs,  const float* __restrict__ bhs,
    float* __restrict__ out, int out_half)
{
  __shared__ __align__(16) char smem[64*416*2];   // 53248 B (im2col / warped alias)
  __shared__ int   cidx[LNK*4*64];
  __shared__ float cwt[LNK*4*64];

  const int t = threadIdx.x;
  const int b = blockIdx.x >> 6;
  const int y = blockIdx.x & 63;
  const int lane = t & 63;
  const int w = t >> 6;

  // bilinear corners for 64 pos x 5 links
  if (t < 320) {
    int pos = t & 63; int l = t >> 6;
    float fx = flows[((b*2*LNK) + 2*l + 0)*HH*WW + y*WW + pos];
    float fy = flows[((b*2*LNK) + 2*l + 1)*HH*WW + y*WW + pos];
    float px = fx + (float)pos;
    float py = fy + (float)y;
    float x0f = floorf(px), y0f = floorf(py);
    float ax = px - x0f, ay = py - y0f;
    int ix0 = (int)x0f, iy0 = (int)y0f;
    #pragma unroll
    for (int k = 0; k < 4; ++k) {
      int dx = k & 1, dy = k >> 1;
      int ix = ix0 + dx, iy = iy0 + dy;
      float wgt = (dx ? ax : 1.f - ax) * (dy ? ay : 1.f - ay);
      bool inb = (ix >= 0 && ix < WW && iy >= 0 && iy < HH);
      int ixc = ix < 0 ? 0 : (ix > WW-1 ? WW-1 : ix);
      int iyc = iy < 0 ? 0 : (iy > HH-1 ? HH-1 : iy);
      cidx[(l*4 + k)*64 + pos] = iyc*WW + ixc;
      cwt [(l*4 + k)*64 + pos] = inb ? wgt : 0.f;
    }
  }

  // im2col B2[pos][k] bf16, k in [0,416) (>=400 zero-padded)
  {
    const float* xp = x + b*CINX*HH*WW;
    for (int i = t; i < 64*416; i += 512) {
      int pos = i / 416; int k = i - pos*416;
      float val = 0.f;
      if (k < 400) {
        int cin = k / 25; int tap = k - cin*25;
        int kh = tap / 5; int kw = tap - kh*5;
        int gy = y + kh - 2, gxp = pos + kw - 2;
        if (gy >= 0 && gy < HH && gxp >= 0 && gxp < WW)
          val = xp[cin*4096 + gy*64 + gxp];
      }
      *(unsigned short*)(smem + SWZ(pos*832 + k*2, pos)) = f2b(val);
    }
  }
  __syncthreads();

  f32x4 accr[4], acch[4], tmph[4];
  #pragma unroll
  for (int f = 0; f < 4; ++f) {
    accr[f] = (f32x4){0.f,0.f,0.f,0.f};
    acch[f] = (f32x4){0.f,0.f,0.f,0.f};
    tmph[f] = (f32x4){0.f,0.f,0.f,0.f};
  }

  // GEMM2: x-conv, 13 K-steps
  #pragma unroll 2
  for (int ks = 0; ks < 13; ++ks) {
    bf16x8 ar = *(const bf16x8*)(xrF + ((ks << 3) + w)*512 + lane*8);
    bf16x8 ah = *(const bf16x8*)(xhF + ((ks << 3) + w)*512 + lane*8);
    int k0 = (ks << 5) + ((lane >> 4) << 3);
    #pragma unroll
    for (int f = 0; f < 4; ++f) {
      int col = (f << 4) + (lane & 15);
      bf16x8 bv = *(const bf16x8*)(smem + SWZ(col*832 + k0*2, col));
      accr[f] = MFMA(ar, bv, accr[f]);
      acch[f] = MFMA(ah, bv, acch[f]);
    }
  }

  // GEMM1: einsum, 5 chunks of K=128
  const float* hp = h + b*CHID*HH*WW;
  #pragma unroll 1
  for (int l = 0; l < 5; ++l) {
    __syncthreads();   // prior reads of smem done
    // gather: pos = lane, c = w*16 + 0..15, pack pairs -> bf16x2 writes
    float w0 = cwt[(l*4+0)*64 + lane], w1 = cwt[(l*4+1)*64 + lane];
    float w2 = cwt[(l*4+2)*64 + lane], w3 = cwt[(l*4+3)*64 + lane];
    int   i0 = cidx[(l*4+0)*64 + lane], i1 = cidx[(l*4+1)*64 + lane];
    int   i2 = cidx[(l*4+2)*64 + lane], i3 = cidx[(l*4+3)*64 + lane];
    const float* hc = hp + (w << 4)*4096;
    #pragma unroll
    for (int jj = 0; jj < 8; ++jj) {
      const float* h0 = hc + (2*jj)*4096;
      const float* h1 = h0 + 4096;
      float a0 = w0*h0[i0]; a0 = fmaf(w1, h0[i1], a0);
      a0 = fmaf(w2, h0[i2], a0); a0 = fmaf(w3, h0[i3], a0);
      float a1 = w0*h1[i0]; a1 = fmaf(w1, h1[i1], a1);
      a1 = fmaf(w2, h1[i2], a1); a1 = fmaf(w3, h1[i3], a1);
      unsigned pr = (unsigned)f2b(a0) | ((unsigned)f2b(a1) << 16);
      int c0 = (w << 4) + 2*jj;
      *(unsigned*)(smem + SWZ(lane*256 + c0*2, lane)) = pr;
    }
    __syncthreads();
    #pragma unroll
    for (int ks = 0; ks < 4; ++ks) {
      bf16x8 ar = *(const bf16x8*)(erF + (((l << 2) + ks)*8 + w)*512 + lane*8);
      bf16x8 ah = *(const bf16x8*)(ehF + (((l << 2) + ks)*8 + w)*512 + lane*8);
      int k0 = (ks << 5) + ((lane >> 4) << 3);
      #pragma unroll
      for (int f = 0; f < 4; ++f) {
        int col = (f << 4) + (lane & 15);
        bf16x8 bv = *(const bf16x8*)(smem + SWZ(col*256 + k0*2, col));
        accr[f] = MFMA(ar, bv, accr[f]);
        tmph[f] = MFMA(ah, bv, tmph[f]);
      }
    }
  }

  // epilogue: r=sigmoid(.), out = leaky(ch + r*th); z cancels.
  const int obase = (b*CHID)*HH*WW + y*WW;
  #pragma unroll
  for (int r = 0; r < 4; ++r) {
    int o = (w << 4) + ((lane >> 4) << 2) + r;
    float br_ = wxrb[o] + brs[o];
    float bh_ = wxhb[o];
    float bt_ = bhs[o];
    #pragma unroll
    for (int f = 0; f < 4; ++f) {
      int pos_ = (f << 4) + (lane & 15);
      float rg = 1.f / (1.f + expf(-(accr[f][r] + br_)));
      float hv = (acch[f][r] + bh_) + rg*(tmph[f][r] + bt_);
      hv = hv >= 0.f ? hv : 0.2f*hv;
      int idx = obase + o*HH*WW + pos_;
      out[idx] = hv;
      out[out_half + idx] = hv;
    }
  }
}

extern "C" void kernel_launch(void* const* d_in, const int* in_sizes, int n_in,
                              void* d_out, int out_size, void* d_ws, size_t ws_size,
                              hipStream_t stream)
{
  const float* x     = (const float*)d_in[0];
  const float* h     = (const float*)d_in[1];
  const float* gx_w  = (const float*)d_in[2];
  const float* gx_b  = (const float*)d_in[3];
  const float* gh_w  = (const float*)d_in[4];
  const float* gh_b  = (const float*)d_in[5];
  const float* gf_w  = (const float*)d_in[6];
  const float* gf_b  = (const float*)d_in[7];
  const float* wxr_w = (const float*)d_in[10];
  const float* wxr_b = (const float*)d_in[11];
  const float* wxh_w = (const float*)d_in[12];
  const float* wxh_b = (const float*)d_in[13];
  const float* whr_w = (const float*)d_in[16];
  const float* whr_b = (const float*)d_in[17];
  const float* whh_w = (const float*)d_in[18];
  const float* whh_b = (const float*)d_in[19];
  float* out = (float*)d_out;
  float* wsf = (float*)d_ws;

  float* f_buf = wsf + OFF_F;
  float* flows = wsf + OFF_FLOWS;
  float* wgT   = wsf + OFF_WG;
  float* wfT   = wsf + OFF_WF;
  float* brs   = wsf + OFF_BRS;
  float* bhs   = wsf + OFF_BHS;
  unsigned short* erF = (unsigned short*)(wsf + OFF_ERF);
  unsigned short* ehF = (unsigned short*)(wsf + OFF_EHF);
  unsigned short* xrF = (unsigned short*)(wsf + OFF_XRF);
  unsigned short* xhF = (unsigned short*)(wsf + OFF_XHF);

  prep_kernel<<<(P_XF + 255)/256, 256, 0, stream>>>(
      wxr_w, wxh_w, whr_w, whh_w, whr_b, whh_b, gx_w, gh_w, gf_w,
      wgT, wfT, brs, bhs, erF, ehF, xrF, xhF);
  fgen2_kernel<<<BATCH*HH, 512, 0, stream>>>(x, h, wgT, gx_b, gh_b, f_buf);
  flowc2_kernel<<<BATCH*HH, 640, 0, stream>>>(f_buf, wfT, gf_b, flows);
  fuse3_kernel<<<BATCH*HH, 512, 0, stream>>>(x, h, flows, erF, ehF, xrF, xhF,
                                             wxr_b, wxh_b, brs, bhs, out, out_size/2);
}

// Round 5
// 481.962 us; speedup vs baseline: 4.7186x; 1.4873x over previous
//
#include <hip/hip_runtime.h>
#include <math.h>

#define HH 64
#define WW 64
#define BATCH 16
#define CINX 16
#define CHID 128
#define LNK 5

// ws layout (floats)
#define OFF_F      0
#define N_F        (BATCH*32*HH*WW)          // 2097152
#define OFF_FLOWS  (OFF_F + N_F)
#define N_FLOWS    (BATCH*2*LNK*HH*WW)       // 655360
#define OFF_WF     (OFF_FLOWS + N_FLOWS)     // 2752512
#define N_WF       (32*25*10)                // 8000
#define OFF_BRS    (OFF_WF + N_WF)
#define OFF_BHS    (OFF_BRS + 128)
#define OFF_ERF    (OFF_BHS + 128)           // einsum frags bf16 (81920 each gate)
#define OFF_EHF    (OFF_ERF + 40960)
#define OFF_XRF    (OFF_EHF + 40960)         // xconv frags bf16 (53248 each gate)
#define OFF_XHF    (OFF_XRF + 26624)
#define OFF_XGF    (OFF_XHF + 26624)         // fgen frags bf16 (138240)
// total = OFF_XGF + 69120 = 2965056 floats ~ 11.9 MB

// prep region boundaries (element indices)
#define P_WF   8000
#define P_B    (P_WF + 128)                  // 8128
#define P_EF   (P_B + 81920)                 // 90048
#define P_XF   (P_EF + 53248)                // 143296
#define P_GF   (P_XF + 138240)               // 281536

typedef short bf16x8 __attribute__((ext_vector_type(8)));
typedef float f32x4  __attribute__((ext_vector_type(4)));
#define MFMA(a,b,c) __builtin_amdgcn_mfma_f32_16x16x32_bf16((a),(b),(c),0,0,0)

__device__ __forceinline__ unsigned short f2b(float f) {
  unsigned u = __builtin_bit_cast(unsigned, f);
  u += 0x7fffu + ((u >> 16) & 1u);           // RNE
  return (unsigned short)(u >> 16);
}

#define SWZ(byte, row) ((byte) ^ (((row) & 7) << 4))

// ---------------- prep: fragment weights, pre-sum biases --------
__global__ __launch_bounds__(256) void prep_kernel(
    const float* __restrict__ wxr_w, const float* __restrict__ wxh_w,
    const float* __restrict__ whr_w, const float* __restrict__ whh_w,
    const float* __restrict__ whr_b, const float* __restrict__ whh_b,
    const float* __restrict__ gx_w,  const float* __restrict__ gh_w,
    const float* __restrict__ gf_w,
    float* __restrict__ wfT,
    float* __restrict__ brs,  float* __restrict__ bhs,
    unsigned short* __restrict__ erF, unsigned short* __restrict__ ehF,
    unsigned short* __restrict__ xrF, unsigned short* __restrict__ xhF,
    unsigned short* __restrict__ xgF)
{
  int i = blockIdx.x * 256 + threadIdx.x;
  if (i < P_WF) {
    int k = i / 10, o = i % 10;              // wfT[k][o], k = cin*25+tap
    int cin = k / 25, tap = k % 25;
    wfT[i] = gf_w[(o*32 + cin)*25 + tap];
  } else if (i < P_B) {
    int o = i - P_WF;
    float sr = 0.f, sh = 0.f;
    for (int l = 0; l < LNK; ++l) { sr += whr_b[l*128 + o]; sh += whh_b[l*128 + o]; }
    brs[o] = sr; bhs[o] = sh;
  } else if (i < P_EF) {
    // einsum A-frags: j = (((l*4+ks)*8+m)*64 + lane)*8 + jj
    int j = i - P_B;
    int jj = j & 7, lane = (j >> 3) & 63, m = (j >> 9) & 7, ks = (j >> 12) & 3, l = j >> 14;
    int o = m*16 + (lane & 15);
    int c = ks*32 + ((lane >> 4) << 3) + jj;
    erF[j] = f2b(whr_w[(l*128 + o)*128 + c]);
    ehF[j] = f2b(whh_w[(l*128 + o)*128 + c]);
  } else if (i < P_XF) {
    // xconv A-frags: j = ((ks*8+m)*64 + lane)*8 + jj, k padded 400->416
    int j = i - P_EF;
    int jj = j & 7, lane = (j >> 3) & 63, m = (j >> 9) & 7, ks = j >> 12;
    int o = m*16 + (lane & 15);
    int k = ks*32 + ((lane >> 4) << 3) + jj;
    xrF[j] = (k < 400) ? f2b(wxr_w[o*400 + k]) : (unsigned short)0;
    xhF[j] = (k < 400) ? f2b(wxh_w[o*400 + k]) : (unsigned short)0;
  } else if (i < P_GF) {
    // fgen A-frags: j = ((((ch*15 + kw*3 + khp)*2 + mo)*64 + lane)*8 + jj
    int j = i - P_XF;
    int jj = j & 7, lane = (j >> 3) & 63;
    int r2 = j >> 9;
    int mo = r2 & 1;
    int r3 = r2 >> 1;
    int khp = r3 % 3, kw = (r3 / 3) % 5, ch = r3 / 15;
    int q = lane >> 4;
    int k = q*8 + jj;
    int kh = khp*2 + (k >> 4);
    int cin_l = k & 15;
    int o = mo*16 + (lane & 15);
    float val = 0.f;
    if (kh < 5) {
      int tap = kh*5 + kw;
      val = (ch == 0) ? gx_w[(o*CINX + cin_l)*25 + tap]
                      : gh_w[(o*CHID + (ch-1)*16 + cin_l)*25 + tap];
    }
    xgF[j] = f2b(val);
  }
}

// ------- fgen3: f = leaky_relu(conv(x,gx)+conv(h,gh)) via MFMA -------
// block=(b,y), 8 waves; wave w: mo=w>>2 (o-stripe), nf=w&3 (pos group).
// Per 16-cin chunk: tile[6][68][16] bf16 (row5=0), 15 MFMA (5kw x 3 kh-pairs).
__global__ __launch_bounds__(512, 4) void fgen3_kernel(
    const float* __restrict__ x, const float* __restrict__ h,
    const unsigned short* __restrict__ xgF,
    const float* __restrict__ gxb, const float* __restrict__ ghb,
    float* __restrict__ f)
{
  __shared__ __align__(16) char tile[6*68*32];   // 13056 B
  const int t = threadIdx.x;
  const int b = blockIdx.x >> 6;
  const int y = blockIdx.x & 63;
  const int lane = t & 63;
  const int w = t >> 6;
  const int mo = w >> 2, nf = w & 3;
  const int q = lane >> 4;
  const int s = q & 1;        // cin half
  const int khq = q >> 1;     // kh offset within pair
  const int cbase = nf*16 + (lane & 15);

  // zero row 5 once
  for (int i = t; i < 544; i += 512) ((unsigned*)(tile + 5*68*32))[i] = 0u;

  f32x4 acc = (f32x4){0.f, 0.f, 0.f, 0.f};

  #pragma unroll 1
  for (int ch = 0; ch < 9; ++ch) {
    const float* src = (ch == 0) ? (x + b*CINX*HH*WW)
                                 : (h + (b*CHID + (ch - 1)*16)*HH*WW);
    __syncthreads();
    for (int i = t; i < 5440; i += 512) {
      int cin = i / 340, rc = i % 340;
      int r = rc / 68, c = rc % 68;
      int gy = y + r - 2, gx = c - 2;
      float v = (gy >= 0 && gy < HH && gx >= 0 && gx < WW)
                  ? src[cin*4096 + gy*64 + gx] : 0.f;
      int byte = ((r*68 + c)*16 + cin)*2;
      *(unsigned short*)(tile + (byte ^ ((c & 1) << 4))) = f2b(v);
    }
    __syncthreads();
    #pragma unroll
    for (int kw = 0; kw < 5; ++kw) {
      #pragma unroll
      for (int khp = 0; khp < 3; ++khp) {
        bf16x8 av = *(const bf16x8*)(xgF + (((ch*15 + kw*3 + khp)*2 + mo)*512) + lane*8);
        int c = cbase + kw;
        int kh = khp*2 + khq;
        int byte = ((kh*68 + c)*16 + s*8)*2;
        bf16x8 bv = *(const bf16x8*)(tile + (byte ^ ((c & 1) << 4)));
        acc = MFMA(av, bv, acc);
      }
    }
  }

  // epilogue: C row=(lane>>4)*4+r -> o_local, col=lane&15 -> pos_local
  #pragma unroll
  for (int r = 0; r < 4; ++r) {
    int o = mo*16 + q*4 + r;
    int pos = nf*16 + (lane & 15);
    float a = acc[r] + gxb[o] + ghb[o];
    f[(b*32 + o)*HH*WW + y*WW + pos] = a >= 0.f ? a : 0.2f*a;
  }
}

// ------- flows = conv(f, gf), row-per-block -------
__global__ __launch_bounds__(640) void flowc2_kernel(
    const float* __restrict__ f, const float* __restrict__ wfT,
    const float* __restrict__ gfb, float* __restrict__ flows)
{
  __shared__ float tile[16*5*68];
  const int t = threadIdx.x;
  const int b = blockIdx.x >> 6;
  const int y = blockIdx.x & 63;
  const int o = t >> 6;
  const int pos = t & 63;

  float acc = gfb[o];

  #pragma unroll 1
  for (int ch = 0; ch < 2; ++ch) {
    const float* src = f + (b*32 + ch*16)*HH*WW;
    __syncthreads();
    for (int i = t; i < 16*5*68; i += 640) {
      int cin = i / 340, r2 = i % 340;
      int rr = r2 / 68, cc = r2 % 68;
      int gy = y + rr - 2, gx = cc - 2;
      tile[i] = (gy >= 0 && gy < HH && gx >= 0 && gx < WW)
                  ? src[cin*HH*WW + gy*WW + gx] : 0.f;
    }
    __syncthreads();
    const float* wbase = wfT + (ch*16*25)*10;
    #pragma unroll 1
    for (int ci = 0; ci < 16; ++ci) {
      #pragma unroll
      for (int kh = 0; kh < 5; ++kh) {
        #pragma unroll
        for (int kw = 0; kw < 5; ++kw) {
          float w = wbase[((ci*5 + kh)*5 + kw)*10 + o];
          acc = fmaf(w, tile[ci*340 + kh*68 + pos + kw], acc);
        }
      }
    }
  }
  flows[(b*10 + o)*HH*WW + y*WW + pos] = acc;
}

// ---------------- fuse3: MFMA warp+gates+output ----------------
__global__ __launch_bounds__(512, 4) void fuse3_kernel(
    const float* __restrict__ x, const float* __restrict__ h,
    const float* __restrict__ flows,
    const unsigned short* __restrict__ erF, const unsigned short* __restrict__ ehF,
    const unsigned short* __restrict__ xrF, const unsigned short* __restrict__ xhF,
    const float* __restrict__ wxrb, const float* __restrict__ wxhb,
    const float* __restrict__ brs,  const float* __restrict__ bhs,
    float* __restrict__ out, int out_half)
{
  __shared__ __align__(16) char smem[64*416*2];   // 53248 B (im2col / warped alias)
  __shared__ int   cidx[LNK*4*64];
  __shared__ float cwt[LNK*4*64];

  const int t = threadIdx.x;
  const int b = blockIdx.x >> 6;
  const int y = blockIdx.x & 63;
  const int lane = t & 63;
  const int w = t >> 6;

  // bilinear corners for 64 pos x 5 links
  if (t < 320) {
    int pos = t & 63; int l = t >> 6;
    float fx = flows[((b*2*LNK) + 2*l + 0)*HH*WW + y*WW + pos];
    float fy = flows[((b*2*LNK) + 2*l + 1)*HH*WW + y*WW + pos];
    float px = fx + (float)pos;
    float py = fy + (float)y;
    float x0f = floorf(px), y0f = floorf(py);
    float ax = px - x0f, ay = py - y0f;
    int ix0 = (int)x0f, iy0 = (int)y0f;
    #pragma unroll
    for (int k = 0; k < 4; ++k) {
      int dx = k & 1, dy = k >> 1;
      int ix = ix0 + dx, iy = iy0 + dy;
      float wgt = (dx ? ax : 1.f - ax) * (dy ? ay : 1.f - ay);
      bool inb = (ix >= 0 && ix < WW && iy >= 0 && iy < HH);
      int ixc = ix < 0 ? 0 : (ix > WW-1 ? WW-1 : ix);
      int iyc = iy < 0 ? 0 : (iy > HH-1 ? HH-1 : iy);
      cidx[(l*4 + k)*64 + pos] = iyc*WW + ixc;
      cwt [(l*4 + k)*64 + pos] = inb ? wgt : 0.f;
    }
  }

  // im2col B2[pos][k] bf16, k in [0,416) (>=400 zero-padded)
  {
    const float* xp = x + b*CINX*HH*WW;
    for (int i = t; i < 64*416; i += 512) {
      int pos = i / 416; int k = i - pos*416;
      float val = 0.f;
      if (k < 400) {
        int cin = k / 25; int tap = k - cin*25;
        int kh = tap / 5; int kw = tap - kh*5;
        int gy = y + kh - 2, gxp = pos + kw - 2;
        if (gy >= 0 && gy < HH && gxp >= 0 && gxp < WW)
          val = xp[cin*4096 + gy*64 + gxp];
      }
      *(unsigned short*)(smem + SWZ(pos*832 + k*2, pos)) = f2b(val);
    }
  }
  __syncthreads();

  f32x4 accr[4], acch[4], tmph[4];
  #pragma unroll
  for (int f = 0; f < 4; ++f) {
    accr[f] = (f32x4){0.f,0.f,0.f,0.f};
    acch[f] = (f32x4){0.f,0.f,0.f,0.f};
    tmph[f] = (f32x4){0.f,0.f,0.f,0.f};
  }

  // GEMM2: x-conv, 13 K-steps
  #pragma unroll 2
  for (int ks = 0; ks < 13; ++ks) {
    bf16x8 ar = *(const bf16x8*)(xrF + ((ks << 3) + w)*512 + lane*8);
    bf16x8 ah = *(const bf16x8*)(xhF + ((ks << 3) + w)*512 + lane*8);
    int k0 = (ks << 5) + ((lane >> 4) << 3);
    #pragma unroll
    for (int f = 0; f < 4; ++f) {
      int col = (f << 4) + (lane & 15);
      bf16x8 bv = *(const bf16x8*)(smem + SWZ(col*832 + k0*2, col));
      accr[f] = MFMA(ar, bv, accr[f]);
      acch[f] = MFMA(ah, bv, acch[f]);
    }
  }

  // GEMM1: einsum, 5 chunks of K=128
  const float* hp = h + b*CHID*HH*WW;
  #pragma unroll 1
  for (int l = 0; l < 5; ++l) {
    __syncthreads();   // prior reads of smem done
    float w0 = cwt[(l*4+0)*64 + lane], w1 = cwt[(l*4+1)*64 + lane];
    float w2 = cwt[(l*4+2)*64 + lane], w3 = cwt[(l*4+3)*64 + lane];
    int   i0 = cidx[(l*4+0)*64 + lane], i1 = cidx[(l*4+1)*64 + lane];
    int   i2 = cidx[(l*4+2)*64 + lane], i3 = cidx[(l*4+3)*64 + lane];
    const float* hc = hp + (w << 4)*4096;
    #pragma unroll
    for (int jj = 0; jj < 8; ++jj) {
      const float* h0 = hc + (2*jj)*4096;
      const float* h1 = h0 + 4096;
      float a0 = w0*h0[i0]; a0 = fmaf(w1, h0[i1], a0);
      a0 = fmaf(w2, h0[i2], a0); a0 = fmaf(w3, h0[i3], a0);
      float a1 = w0*h1[i0]; a1 = fmaf(w1, h1[i1], a1);
      a1 = fmaf(w2, h1[i2], a1); a1 = fmaf(w3, h1[i3], a1);
      unsigned pr = (unsigned)f2b(a0) | ((unsigned)f2b(a1) << 16);
      int c0 = (w << 4) + 2*jj;
      *(unsigned*)(smem + SWZ(lane*256 + c0*2, lane)) = pr;
    }
    __syncthreads();
    #pragma unroll
    for (int ks = 0; ks < 4; ++ks) {
      bf16x8 ar = *(const bf16x8*)(erF + (((l << 2) + ks)*8 + w)*512 + lane*8);
      bf16x8 ah = *(const bf16x8*)(ehF + (((l << 2) + ks)*8 + w)*512 + lane*8);
      int k0 = (ks << 5) + ((lane >> 4) << 3);
      #pragma unroll
      for (int f = 0; f < 4; ++f) {
        int col = (f << 4) + (lane & 15);
        bf16x8 bv = *(const bf16x8*)(smem + SWZ(col*256 + k0*2, col));
        accr[f] = MFMA(ar, bv, accr[f]);
        tmph[f] = MFMA(ah, bv, tmph[f]);
      }
    }
  }

  // epilogue: r=sigmoid(.), out = leaky(ch + r*th); z cancels.
  const int obase = (b*CHID)*HH*WW + y*WW;
  #pragma unroll
  for (int r = 0; r < 4; ++r) {
    int o = (w << 4) + ((lane >> 4) << 2) + r;
    float br_ = wxrb[o] + brs[o];
    float bh_ = wxhb[o];
    float bt_ = bhs[o];
    #pragma unroll
    for (int f = 0; f < 4; ++f) {
      int pos_ = (f << 4) + (lane & 15);
      float rg = 1.f / (1.f + expf(-(accr[f][r] + br_)));
      float hv = (acch[f][r] + bh_) + rg*(tmph[f][r] + bt_);
      hv = hv >= 0.f ? hv : 0.2f*hv;
      int idx = obase + o*HH*WW + pos_;
      out[idx] = hv;
      out[out_half + idx] = hv;
    }
  }
}

extern "C" void kernel_launch(void* const* d_in, const int* in_sizes, int n_in,
                              void* d_out, int out_size, void* d_ws, size_t ws_size,
                              hipStream_t stream)
{
  const float* x     = (const float*)d_in[0];
  const float* h     = (const float*)d_in[1];
  const float* gx_w  = (const float*)d_in[2];
  const float* gx_b  = (const float*)d_in[3];
  const float* gh_w  = (const float*)d_in[4];
  const float* gh_b  = (const float*)d_in[5];
  const float* gf_w  = (const float*)d_in[6];
  const float* gf_b  = (const float*)d_in[7];
  const float* wxr_w = (const float*)d_in[10];
  const float* wxr_b = (const float*)d_in[11];
  const float* wxh_w = (const float*)d_in[12];
  const float* wxh_b = (const float*)d_in[13];
  const float* whr_w = (const float*)d_in[16];
  const float* whr_b = (const float*)d_in[17];
  const float* whh_w = (const float*)d_in[18];
  const float* whh_b = (const float*)d_in[19];
  float* out = (float*)d_out;
  float* wsf = (float*)d_ws;

  float* f_buf = wsf + OFF_F;
  float* flows = wsf + OFF_FLOWS;
  float* wfT   = wsf + OFF_WF;
  float* brs   = wsf + OFF_BRS;
  float* bhs   = wsf + OFF_BHS;
  unsigned short* erF = (unsigned short*)(wsf + OFF_ERF);
  unsigned short* ehF = (unsigned short*)(wsf + OFF_EHF);
  unsigned short* xrF = (unsigned short*)(wsf + OFF_XRF);
  unsigned short* xhF = (unsigned short*)(wsf + OFF_XHF);
  unsigned short* xgF = (unsigned short*)(wsf + OFF_XGF);

  prep_kernel<<<(P_GF + 255)/256, 256, 0, stream>>>(
      wxr_w, wxh_w, whr_w, whh_w, whr_b, whh_b, gx_w, gh_w, gf_w,
      wfT, brs, bhs, erF, ehF, xrF, xhF, xgF);
  fgen3_kernel<<<BATCH*HH, 512, 0, stream>>>(x, h, xgF, gx_b, gh_b, f_buf);
  flowc2_kernel<<<BATCH*HH, 640, 0, stream>>>(f_buf, wfT, gf_b, flows);
  fuse3_kernel<<<BATCH*HH, 512, 0, stream>>>(x, h, flows, erF, ehF, xrF, xhF,
                                             wxr_b, wxh_b, brs, bhs, out, out_size/2);
}

// Round 6
// 380.163 us; speedup vs baseline: 5.9822x; 1.2678x over previous
//
#include <hip/hip_runtime.h>
#include <math.h>

#define HH 64
#define WW 64
#define BATCH 16
#define CINX 16
#define CHID 128
#define LNK 5

// ws layout (floats)
#define OFF_F      0
#define N_F        (BATCH*32*HH*WW)          // 2097152
#define OFF_FLOWS  (OFF_F + N_F)
#define N_FLOWS    (BATCH*2*LNK*HH*WW)       // 655360
#define OFF_WF     (OFF_FLOWS + N_FLOWS)     // 2752512
#define N_WF       (32*25*10)                // 8000
#define OFF_BRS    (OFF_WF + N_WF)
#define OFF_BHS    (OFF_BRS + 128)
#define OFF_ERF    (OFF_BHS + 128)           // einsum frags bf16 (81920 each gate)
#define OFF_EHF    (OFF_ERF + 40960)
#define OFF_XRF    (OFF_EHF + 40960)         // xconv frags bf16 (53248 each gate)
#define OFF_XHF    (OFF_XRF + 26624)
#define OFF_XGF    (OFF_XHF + 26624)         // fgen frags bf16 (138240)

// prep region boundaries (element indices)
#define P_WF   8000
#define P_B    (P_WF + 128)                  // 8128
#define P_EF   (P_B + 81920)                 // 90048
#define P_XF   (P_EF + 53248)                // 143296
#define P_GF   (P_XF + 138240)               // 281536

typedef short bf16x8 __attribute__((ext_vector_type(8)));
typedef float f32x4  __attribute__((ext_vector_type(4)));
#define MFMA(a,b,c) __builtin_amdgcn_mfma_f32_16x16x32_bf16((a),(b),(c),0,0,0)

__device__ __forceinline__ unsigned short f2b(float f) {
  unsigned u = __builtin_bit_cast(unsigned, f);
  u += 0x7fffu + ((u >> 16) & 1u);           // RNE
  return (unsigned short)(u >> 16);
}

#define SWZ(byte, row) ((byte) ^ (((row) & 7) << 4))

// XCD-aware bijective swizzle: grid = 1024 = 8 XCDs x 128.
// physical p -> XCD p%8; give each XCD a contiguous (b,y) range so
// adjacent-y blocks (which share h rows y+-4) hit the same L2.
__device__ __forceinline__ int xcd_swz(int p) {
  return (p & 7) * 128 + (p >> 3);
}

// ---------------- prep: fragment weights, pre-sum biases --------
__global__ __launch_bounds__(256) void prep_kernel(
    const float* __restrict__ wxr_w, const float* __restrict__ wxh_w,
    const float* __restrict__ whr_w, const float* __restrict__ whh_w,
    const float* __restrict__ whr_b, const float* __restrict__ whh_b,
    const float* __restrict__ gx_w,  const float* __restrict__ gh_w,
    const float* __restrict__ gf_w,
    float* __restrict__ wfT,
    float* __restrict__ brs,  float* __restrict__ bhs,
    unsigned short* __restrict__ erF, unsigned short* __restrict__ ehF,
    unsigned short* __restrict__ xrF, unsigned short* __restrict__ xhF,
    unsigned short* __restrict__ xgF)
{
  int i = blockIdx.x * 256 + threadIdx.x;
  if (i < P_WF) {
    int k = i / 10, o = i % 10;              // wfT[k][o], k = cin*25+tap
    int cin = k / 25, tap = k % 25;
    wfT[i] = gf_w[(o*32 + cin)*25 + tap];
  } else if (i < P_B) {
    int o = i - P_WF;
    float sr = 0.f, sh = 0.f;
    for (int l = 0; l < LNK; ++l) { sr += whr_b[l*128 + o]; sh += whh_b[l*128 + o]; }
    brs[o] = sr; bhs[o] = sh;
  } else if (i < P_EF) {
    // einsum A-frags: j = (((l*4+ks)*8+m)*64 + lane)*8 + jj
    int j = i - P_B;
    int jj = j & 7, lane = (j >> 3) & 63, m = (j >> 9) & 7, ks = (j >> 12) & 3, l = j >> 14;
    int o = m*16 + (lane & 15);
    int c = ks*32 + ((lane >> 4) << 3) + jj;
    erF[j] = f2b(whr_w[(l*128 + o)*128 + c]);
    ehF[j] = f2b(whh_w[(l*128 + o)*128 + c]);
  } else if (i < P_XF) {
    // xconv A-frags: j = ((ks*8+m)*64 + lane)*8 + jj, k padded 400->416
    int j = i - P_EF;
    int jj = j & 7, lane = (j >> 3) & 63, m = (j >> 9) & 7, ks = j >> 12;
    int o = m*16 + (lane & 15);
    int k = ks*32 + ((lane >> 4) << 3) + jj;
    xrF[j] = (k < 400) ? f2b(wxr_w[o*400 + k]) : (unsigned short)0;
    xhF[j] = (k < 400) ? f2b(wxh_w[o*400 + k]) : (unsigned short)0;
  } else if (i < P_GF) {
    // fgen A-frags: j = ((((ch*15 + kw*3 + khp)*2 + mo)*64 + lane)*8 + jj
    int j = i - P_XF;
    int jj = j & 7, lane = (j >> 3) & 63;
    int r2 = j >> 9;
    int mo = r2 & 1;
    int r3 = r2 >> 1;
    int khp = r3 % 3, kw = (r3 / 3) % 5, ch = r3 / 15;
    int q = lane >> 4;
    int k = q*8 + jj;
    int kh = khp*2 + (k >> 4);
    int cin_l = k & 15;
    int o = mo*16 + (lane & 15);
    float val = 0.f;
    if (kh < 5) {
      int tap = kh*5 + kw;
      val = (ch == 0) ? gx_w[(o*CINX + cin_l)*25 + tap]
                      : gh_w[(o*CHID + (ch-1)*16 + cin_l)*25 + tap];
    }
    xgF[j] = f2b(val);
  }
}

// ------- fgen3: f = leaky_relu(conv(x,gx)+conv(h,gh)) via MFMA -------
__global__ __launch_bounds__(512, 4) void fgen3_kernel(
    const float* __restrict__ x, const float* __restrict__ h,
    const unsigned short* __restrict__ xgF,
    const float* __restrict__ gxb, const float* __restrict__ ghb,
    float* __restrict__ f)
{
  __shared__ __align__(16) char tile[6*68*32];   // 13056 B
  const int t = threadIdx.x;
  const int lb = xcd_swz(blockIdx.x);
  const int b = lb >> 6;
  const int y = lb & 63;
  const int lane = t & 63;
  const int w = t >> 6;
  const int mo = w >> 2, nf = w & 3;
  const int q = lane >> 4;
  const int s = q & 1;        // cin half
  const int khq = q >> 1;     // kh offset within pair
  const int cbase = nf*16 + (lane & 15);

  // zero row 5 once
  for (int i = t; i < 544; i += 512) ((unsigned*)(tile + 5*68*32))[i] = 0u;

  f32x4 acc = (f32x4){0.f, 0.f, 0.f, 0.f};

  #pragma unroll 1
  for (int ch = 0; ch < 9; ++ch) {
    const float* src = (ch == 0) ? (x + b*CINX*HH*WW)
                                 : (h + (b*CHID + (ch - 1)*16)*HH*WW);
    __syncthreads();
    for (int i = t; i < 5440; i += 512) {
      int cin = i / 340, rc = i % 340;
      int r = rc / 68, c = rc % 68;
      int gy = y + r - 2, gx = c - 2;
      float v = (gy >= 0 && gy < HH && gx >= 0 && gx < WW)
                  ? src[cin*4096 + gy*64 + gx] : 0.f;
      int byte = ((r*68 + c)*16 + cin)*2;
      *(unsigned short*)(tile + (byte ^ ((c & 1) << 4))) = f2b(v);
    }
    __syncthreads();
    #pragma unroll
    for (int kw = 0; kw < 5; ++kw) {
      #pragma unroll
      for (int khp = 0; khp < 3; ++khp) {
        bf16x8 av = *(const bf16x8*)(xgF + (((ch*15 + kw*3 + khp)*2 + mo)*512) + lane*8);
        int c = cbase + kw;
        int kh = khp*2 + khq;
        int byte = ((kh*68 + c)*16 + s*8)*2;
        bf16x8 bv = *(const bf16x8*)(tile + (byte ^ ((c & 1) << 4)));
        acc = MFMA(av, bv, acc);
      }
    }
  }

  // epilogue: C row=(lane>>4)*4+r -> o_local, col=lane&15 -> pos_local
  #pragma unroll
  for (int r = 0; r < 4; ++r) {
    int o = mo*16 + q*4 + r;
    int pos = nf*16 + (lane & 15);
    float a = acc[r] + gxb[o] + ghb[o];
    f[(b*32 + o)*HH*WW + y*WW + pos] = a >= 0.f ? a : 0.2f*a;
  }
}

// ------- flows = conv(f, gf), row-per-block -------
__global__ __launch_bounds__(640) void flowc2_kernel(
    const float* __restrict__ f, const float* __restrict__ wfT,
    const float* __restrict__ gfb, float* __restrict__ flows)
{
  __shared__ float tile[16*5*68];
  const int t = threadIdx.x;
  const int lb = xcd_swz(blockIdx.x);
  const int b = lb >> 6;
  const int y = lb & 63;
  const int o = t >> 6;
  const int pos = t & 63;

  float acc = gfb[o];

  #pragma unroll 1
  for (int ch = 0; ch < 2; ++ch) {
    const float* src = f + (b*32 + ch*16)*HH*WW;
    __syncthreads();
    for (int i = t; i < 16*5*68; i += 640) {
      int cin = i / 340, r2 = i % 340;
      int rr = r2 / 68, cc = r2 % 68;
      int gy = y + rr - 2, gx = cc - 2;
      tile[i] = (gy >= 0 && gy < HH && gx >= 0 && gx < WW)
                  ? src[cin*HH*WW + gy*WW + gx] : 0.f;
    }
    __syncthreads();
    const float* wbase = wfT + (ch*16*25)*10;
    #pragma unroll 1
    for (int ci = 0; ci < 16; ++ci) {
      #pragma unroll
      for (int kh = 0; kh < 5; ++kh) {
        #pragma unroll
        for (int kw = 0; kw < 5; ++kw) {
          float w = wbase[((ci*5 + kh)*5 + kw)*10 + o];
          acc = fmaf(w, tile[ci*340 + kh*68 + pos + kw], acc);
        }
      }
    }
  }
  flows[(b*10 + o)*HH*WW + y*WW + pos] = acc;
}

// ---------------- fuse3: MFMA warp+gates+output ----------------
__global__ __launch_bounds__(512, 4) void fuse3_kernel(
    const float* __restrict__ x, const float* __restrict__ h,
    const float* __restrict__ flows,
    const unsigned short* __restrict__ erF, const unsigned short* __restrict__ ehF,
    const unsigned short* __restrict__ xrF, const unsigned short* __restrict__ xhF,
    const float* __restrict__ wxrb, const float* __restrict__ wxhb,
    const float* __restrict__ brs,  const float* __restrict__ bhs,
    float* __restrict__ out, int out_half)
{
  __shared__ __align__(16) char smem[64*416*2];   // 53248 B (im2col / warped alias)
  __shared__ int   cidx[LNK*4*64];
  __shared__ float cwt[LNK*4*64];

  const int t = threadIdx.x;
  const int lb = xcd_swz(blockIdx.x);
  const int b = lb >> 6;
  const int y = lb & 63;
  const int lane = t & 63;
  const int w = t >> 6;

  // bilinear corners for 64 pos x 5 links
  if (t < 320) {
    int pos = t & 63; int l = t >> 6;
    float fx = flows[((b*2*LNK) + 2*l + 0)*HH*WW + y*WW + pos];
    float fy = flows[((b*2*LNK) + 2*l + 1)*HH*WW + y*WW + pos];
    float px = fx + (float)pos;
    float py = fy + (float)y;
    float x0f = floorf(px), y0f = floorf(py);
    float ax = px - x0f, ay = py - y0f;
    int ix0 = (int)x0f, iy0 = (int)y0f;
    #pragma unroll
    for (int k = 0; k < 4; ++k) {
      int dx = k & 1, dy = k >> 1;
      int ix = ix0 + dx, iy = iy0 + dy;
      float wgt = (dx ? ax : 1.f - ax) * (dy ? ay : 1.f - ay);
      bool inb = (ix >= 0 && ix < WW && iy >= 0 && iy < HH);
      int ixc = ix < 0 ? 0 : (ix > WW-1 ? WW-1 : ix);
      int iyc = iy < 0 ? 0 : (iy > HH-1 ? HH-1 : iy);
      cidx[(l*4 + k)*64 + pos] = iyc*WW + ixc;
      cwt [(l*4 + k)*64 + pos] = inb ? wgt : 0.f;
    }
  }

  // im2col B2[pos][k] bf16, k in [0,416) (>=400 zero-padded)
  {
    const float* xp = x + b*CINX*HH*WW;
    for (int i = t; i < 64*416; i += 512) {
      int pos = i / 416; int k = i - pos*416;
      float val = 0.f;
      if (k < 400) {
        int cin = k / 25; int tap = k - cin*25;
        int kh = tap / 5; int kw = tap - kh*5;
        int gy = y + kh - 2, gxp = pos + kw - 2;
        if (gy >= 0 && gy < HH && gxp >= 0 && gxp < WW)
          val = xp[cin*4096 + gy*64 + gxp];
      }
      *(unsigned short*)(smem + SWZ(pos*832 + k*2, pos)) = f2b(val);
    }
  }
  __syncthreads();

  f32x4 accr[4], acch[4], tmph[4];
  #pragma unroll
  for (int f = 0; f < 4; ++f) {
    accr[f] = (f32x4){0.f,0.f,0.f,0.f};
    acch[f] = (f32x4){0.f,0.f,0.f,0.f};
    tmph[f] = (f32x4){0.f,0.f,0.f,0.f};
  }

  // GEMM2: x-conv, 13 K-steps
  #pragma unroll 2
  for (int ks = 0; ks < 13; ++ks) {
    bf16x8 ar = *(const bf16x8*)(xrF + ((ks << 3) + w)*512 + lane*8);
    bf16x8 ah = *(const bf16x8*)(xhF + ((ks << 3) + w)*512 + lane*8);
    int k0 = (ks << 5) + ((lane >> 4) << 3);
    #pragma unroll
    for (int f = 0; f < 4; ++f) {
      int col = (f << 4) + (lane & 15);
      bf16x8 bv = *(const bf16x8*)(smem + SWZ(col*832 + k0*2, col));
      accr[f] = MFMA(ar, bv, accr[f]);
      acch[f] = MFMA(ah, bv, acch[f]);
    }
  }

  // GEMM1: einsum, 5 chunks of K=128
  const float* hp = h + b*CHID*HH*WW;
  #pragma unroll 1
  for (int l = 0; l < 5; ++l) {
    __syncthreads();   // prior reads of smem done
    float w0 = cwt[(l*4+0)*64 + lane], w1 = cwt[(l*4+1)*64 + lane];
    float w2 = cwt[(l*4+2)*64 + lane], w3 = cwt[(l*4+3)*64 + lane];
    int   i0 = cidx[(l*4+0)*64 + lane], i1 = cidx[(l*4+1)*64 + lane];
    int   i2 = cidx[(l*4+2)*64 + lane], i3 = cidx[(l*4+3)*64 + lane];
    const float* hc = hp + (w << 4)*4096;
    #pragma unroll
    for (int jj = 0; jj < 8; ++jj) {
      const float* h0 = hc + (2*jj)*4096;
      const float* h1 = h0 + 4096;
      float a0 = w0*h0[i0]; a0 = fmaf(w1, h0[i1], a0);
      a0 = fmaf(w2, h0[i2], a0); a0 = fmaf(w3, h0[i3], a0);
      float a1 = w0*h1[i0]; a1 = fmaf(w1, h1[i1], a1);
      a1 = fmaf(w2, h1[i2], a1); a1 = fmaf(w3, h1[i3], a1);
      unsigned pr = (unsigned)f2b(a0) | ((unsigned)f2b(a1) << 16);
      int c0 = (w << 4) + 2*jj;
      *(unsigned*)(smem + SWZ(lane*256 + c0*2, lane)) = pr;
    }
    __syncthreads();
    #pragma unroll
    for (int ks = 0; ks < 4; ++ks) {
      bf16x8 ar = *(const bf16x8*)(erF + (((l << 2) + ks)*8 + w)*512 + lane*8);
      bf16x8 ah = *(const bf16x8*)(ehF + (((l << 2) + ks)*8 + w)*512 + lane*8);
      int k0 = (ks << 5) + ((lane >> 4) << 3);
      #pragma unroll
      for (int f = 0; f < 4; ++f) {
        int col = (f << 4) + (lane & 15);
        bf16x8 bv = *(const bf16x8*)(smem + SWZ(col*256 + k0*2, col));
        accr[f] = MFMA(ar, bv, accr[f]);
        tmph[f] = MFMA(ah, bv, tmph[f]);
      }
    }
  }

  // epilogue: r=sigmoid(.), out = leaky(ch + r*th); z cancels.
  const int obase = (b*CHID)*HH*WW + y*WW;
  #pragma unroll
  for (int r = 0; r < 4; ++r) {
    int o = (w << 4) + ((lane >> 4) << 2) + r;
    float br_ = wxrb[o] + brs[o];
    float bh_ = wxhb[o];
    float bt_ = bhs[o];
    #pragma unroll
    for (int f = 0; f < 4; ++f) {
      int pos_ = (f << 4) + (lane & 15);
      float rg = 1.f / (1.f + expf(-(accr[f][r] + br_)));
      float hv = (acch[f][r] + bh_) + rg*(tmph[f][r] + bt_);
      hv = hv >= 0.f ? hv : 0.2f*hv;
      int idx = obase + o*HH*WW + pos_;
      out[idx] = hv;
      out[out_half + idx] = hv;
    }
  }
}

extern "C" void kernel_launch(void* const* d_in, const int* in_sizes, int n_in,
                              void* d_out, int out_size, void* d_ws, size_t ws_size,
                              hipStream_t stream)
{
  const float* x     = (const float*)d_in[0];
  const float* h     = (const float*)d_in[1];
  const float* gx_w  = (const float*)d_in[2];
  const float* gx_b  = (const float*)d_in[3];
  const float* gh_w  = (const float*)d_in[4];
  const float* gh_b  = (const float*)d_in[5];
  const float* gf_w  = (const float*)d_in[6];
  const float* gf_b  = (const float*)d_in[7];
  const float* wxr_w = (const float*)d_in[10];
  const float* wxr_b = (const float*)d_in[11];
  const float* wxh_w = (const float*)d_in[12];
  const float* wxh_b = (const float*)d_in[13];
  const float* whr_w = (const float*)d_in[16];
  const float* whr_b = (const float*)d_in[17];
  const float* whh_w = (const float*)d_in[18];
  const float* whh_b = (const float*)d_in[19];
  float* out = (float*)d_out;
  float* wsf = (float*)d_ws;

  float* f_buf = wsf + OFF_F;
  float* flows = wsf + OFF_FLOWS;
  float* wfT   = wsf + OFF_WF;
  float* brs   = wsf + OFF_BRS;
  float* bhs   = wsf + OFF_BHS;
  unsigned short* erF = (unsigned short*)(wsf + OFF_ERF);
  unsigned short* ehF = (unsigned short*)(wsf + OFF_EHF);
  unsigned short* xrF = (unsigned short*)(wsf + OFF_XRF);
  unsigned short* xhF = (unsigned short*)(wsf + OFF_XHF);
  unsigned short* xgF = (unsigned short*)(wsf + OFF_XGF);

  prep_kernel<<<(P_GF + 255)/256, 256, 0, stream>>>(
      wxr_w, wxh_w, whr_w, whh_w, whr_b, whh_b, gx_w, gh_w, gf_w,
      wfT, brs, bhs, erF, ehF, xrF, xhF, xgF);
  fgen3_kernel<<<BATCH*HH, 512, 0, stream>>>(x, h, xgF, gx_b, gh_b, f_buf);
  flowc2_kernel<<<BATCH*HH, 640, 0, stream>>>(f_buf, wfT, gf_b, flows);
  fuse3_kernel<<<BATCH*HH, 512, 0, stream>>>(x, h, flows, erF, ehF, xrF, xhF,
                                             wxr_b, wxh_b, brs, bhs, out, out_size/2);
}